// Round 6
// baseline (6860.166 us; speedup 1.0000x reference)
//
#include <hip/hip_runtime.h>
#include <stdint.h>

// PolicyCoreRNN: LSTM, B=1024, T=64, H=I=512.
// Round 6: round-5 structure (batch-decomposed persistent recurrence, no grid
// sync) with the Hw scratch-pitch bug fixed: wave owns 128 h-cols, so pitch
// must be >=128 shorts. Use 144 (72 dw = 8 mod 32 banks -> conflict-free
// 4rowx8dw writes). xq prefetch moved before the MFMA loop (issue-early).

// ---------- round-1 (fallback) ws layout ----------
#define WC_OFF   0u
#define HF_OFF   4194304u
#define CF_OFF   5242880u
#define BIAS_OFF 7340032u
// ---------- fast-path ws layout (bytes) ----------
#define F_WIH   0u           // 2 MiB  bf16 W_ih frags (cb*16+ks)*1024
#define F_WHH   2097152u     // 2 MiB  bf16 W_hh frags
#define F_BIAS  6291456u     // 8 KiB  f32 b_ih+b_hh
#define F_XBF   7340032u     // 64 MiB bf16 x frags ((t*64+mb)*16+ks)*1024
#define F_XPROJ 74448896u    // 256 MiB bf16 x_proj D-frags ((t*64+mb)*128+n)*512
#define F_NEED  342884352u
// out (f32 elements): x | new_rnn_states | h_stack | c_stack
#define OUT_RNN  33554432u
#define OUT_HS   34603008u
#define OUT_CS   68157440u

typedef __attribute__((ext_vector_type(4))) float f32x4;
typedef __attribute__((ext_vector_type(8))) short s16x8;
typedef __attribute__((ext_vector_type(4))) unsigned int u32x4;
typedef __attribute__((ext_vector_type(4))) unsigned short u16x4;

__device__ __forceinline__ unsigned short f2bf(float f) {
  union { float f; unsigned int u; } v; v.f = f;
  return (unsigned short)((v.u + 0x7FFFu + ((v.u >> 16) & 1u)) >> 16);
}
__device__ __forceinline__ float bf2f(unsigned short s) {
  union { unsigned int u; float f; } v; v.u = ((unsigned int)s) << 16;
  return v.f;
}
__device__ __forceinline__ unsigned int pack2(float a, float b) {
  return (unsigned int)f2bf(a) | ((unsigned int)f2bf(b) << 16);
}
__device__ __forceinline__ float sigm(float x) { return 1.0f / (1.0f + __expf(-x)); }

__device__ __forceinline__ void gl_lds16(const void* g, void* lds) {
  __builtin_amdgcn_global_load_lds(
      (const __attribute__((address_space(1))) unsigned int*)g,
      (__attribute__((address_space(3))) unsigned int*)lds, 16, 0, 0);
}

// Fragment conventions (16x16x32 bf16 MFMA):
//  A/B input frag (1KB): lane l holds index (l&15) of the 16-dim, k = ks*32+(l>>4)*8+e.
//  D frag: col = l&15 (B dim), row = (l>>4)*4 + reg (A dim).  [m89-verified]

// ====================== FAST PATH ======================

__global__ void __launch_bounds__(256) prep_fast(
    const float* __restrict__ xg, const float* __restrict__ Wih,
    const float* __restrict__ Whh, const float* __restrict__ bih,
    const float* __restrict__ bhh, unsigned char* __restrict__ ws) {
  unsigned int tid = blockIdx.x * 256u + threadIdx.x;
  unsigned short* wih_f = (unsigned short*)(ws + F_WIH);
  unsigned short* whh_f = (unsigned short*)(ws + F_WHH);
  float* bias = (float*)(ws + F_BIAS);
  unsigned short* xbf = (unsigned short*)(ws + F_XBF);
  if (tid < 131072u) {
    // W_ih frags: frag=(cb<128, ks<16); col=cb*16+(l&15); k0=ks*32+(l>>4)*8
    unsigned int frag = tid >> 6, l = tid & 63u;
    unsigned int cb = frag >> 4, ks = frag & 15u;
    unsigned int g  = cb * 16u + (l & 15u);
    unsigned int k0 = ks * 32u + ((l >> 4) << 3);
    const float* src = Wih + (size_t)g * 512u + k0;
    u32x4 p;
    p.x = pack2(src[0], src[1]); p.y = pack2(src[2], src[3]);
    p.z = pack2(src[4], src[5]); p.w = pack2(src[6], src[7]);
    *(u32x4*)(wih_f + (size_t)frag * 512u + l * 8u) = p;
  } else if (tid < 262144u) {
    unsigned int t2 = tid - 131072u;
    unsigned int frag = t2 >> 6, l = t2 & 63u;
    unsigned int cb = frag >> 4, ks = frag & 15u;
    unsigned int g  = cb * 16u + (l & 15u);
    unsigned int k0 = ks * 32u + ((l >> 4) << 3);
    const float* src = Whh + (size_t)g * 512u + k0;
    u32x4 p;
    p.x = pack2(src[0], src[1]); p.y = pack2(src[2], src[3]);
    p.z = pack2(src[4], src[5]); p.w = pack2(src[6], src[7]);
    *(u32x4*)(whh_f + (size_t)frag * 512u + l * 8u) = p;
  } else if (tid < 264192u) {
    unsigned int g = tid - 262144u;
    bias[g] = bih[g] + bhh[g];
  } else if (tid < 4458496u) {
    // x frags: frag=(t<64, mb<64, ks<16); b=mb*16+(l&15); k0=ks*32+(l>>4)*8
    unsigned int t2 = tid - 264192u;
    unsigned int frag = t2 >> 6, l = t2 & 63u;
    unsigned int ks = frag & 15u, mb = (frag >> 4) & 63u, t = frag >> 10;
    unsigned int b  = mb * 16u + (l & 15u);
    unsigned int k0 = ks * 32u + ((l >> 4) << 3);
    const float* src = xg + ((size_t)(b * 64u + t)) * 512u + k0;
    u32x4 p;
    p.x = pack2(src[0], src[1]); p.y = pack2(src[2], src[3]);
    p.z = pack2(src[4], src[5]); p.w = pack2(src[6], src[7]);
    *(u32x4*)(xbf + (size_t)frag * 512u + l * 8u) = p;
  }
}

// Big GEMM: x_proj[t] = x_t @ W_ih^T + bias, bf16 D-frag output.
// grid 8192 = t(64) x mtile(8) x ntile(16); tile 128M x 128N, K=512, BK=64.
__global__ void __launch_bounds__(256) gemm_xproj(unsigned char* __restrict__ ws) {
  const unsigned short* xbf = (const unsigned short*)(ws + F_XBF);
  const unsigned short* wih = (const unsigned short*)(ws + F_WIH);
  const float* bias = (const float*)(ws + F_BIAS);
  unsigned short* xproj = (unsigned short*)(ws + F_XPROJ);

  __shared__ __align__(16) unsigned char smem[65536];
  const int tid = threadIdx.x;
  const int w = tid >> 6, l = tid & 63;
  const int mh = w & 1, nh = w >> 1;
  const int bid = blockIdx.x;
  const int t = bid >> 7, mtile = (bid >> 4) & 7, ntile = bid & 15;

  f32x4 acc[4][4];
  {
    f32x4 z = {0.f, 0.f, 0.f, 0.f};
    #pragma unroll
    for (int i = 0; i < 4; ++i)
      #pragma unroll
      for (int j = 0; j < 4; ++j) acc[i][j] = z;
  }

  auto stage = [&](int kc, int buf) {
    unsigned char* ab = smem + buf * 16384;
    unsigned char* bb = smem + 32768 + buf * 16384;
    #pragma unroll
    for (int j = 0; j < 4; ++j) {
      int idx = w * 4 + j;
      int mb_l = idx >> 1, ksl = idx & 1;
      size_t frag = (size_t)(t * 64 + mtile * 8 + mb_l) * 16u + kc * 2 + ksl;
      gl_lds16(xbf + (frag * 64u + l) * 8u, ab + idx * 1024);
    }
    #pragma unroll
    for (int j = 0; j < 4; ++j) {
      int idx = w * 4 + j;
      int cb_l = idx >> 1, ksl = idx & 1;
      size_t frag = (size_t)(ntile * 8 + cb_l) * 16u + kc * 2 + ksl;
      gl_lds16(wih + (frag * 64u + l) * 8u, bb + idx * 1024);
    }
  };

  stage(0, 0);
  __syncthreads();
  for (int kc = 0; kc < 8; ++kc) {
    int cur = kc & 1;
    if (kc < 7) stage(kc + 1, cur ^ 1);
    unsigned char* ab = smem + cur * 16384;
    unsigned char* bb = smem + 32768 + cur * 16384;
    s16x8 afr[4][2], bfr[4][2];
    #pragma unroll
    for (int m = 0; m < 4; ++m)
      #pragma unroll
      for (int ksl = 0; ksl < 2; ++ksl)
        afr[m][ksl] = *(const s16x8*)(ab + ((mh * 4 + m) * 2 + ksl) * 1024 + l * 16);
    #pragma unroll
    for (int n = 0; n < 4; ++n)
      #pragma unroll
      for (int ksl = 0; ksl < 2; ++ksl)
        bfr[n][ksl] = *(const s16x8*)(bb + ((nh * 4 + n) * 2 + ksl) * 1024 + l * 16);
    #pragma unroll
    for (int m = 0; m < 4; ++m)
      #pragma unroll
      for (int n = 0; n < 4; ++n)
        #pragma unroll
        for (int ksl = 0; ksl < 2; ++ksl)
          acc[m][n] = __builtin_amdgcn_mfma_f32_16x16x32_bf16(
              afr[m][ksl], bfr[n][ksl], acc[m][n], 0, 0, 0);
    __syncthreads();
  }

  #pragma unroll
  for (int m = 0; m < 4; ++m) {
    int mb_abs = mtile * 8 + mh * 4 + m;
    #pragma unroll
    for (int n = 0; n < 4; ++n) {
      int n_abs = ntile * 8 + nh * 4 + n;
      float bc = bias[n_abs * 16 + (l & 15)];
      u16x4 p;
      #pragma unroll
      for (int r = 0; r < 4; ++r) p[r] = f2bf(acc[m][n][r] + bc);
      *(u16x4*)(xproj + ((size_t)(t * 64 + mb_abs) * 128u + n_abs) * 256u + l * 4u) = p;
    }
  }
}

// Persistent batch-decomposed recurrence: 32 blocks x 256 threads.
// Block owns rows [blk*32, blk*32+32), ALL 512 h-cols. Wave w owns hcols
// [w*128, (w+1)*128). h-state = 32 A-frags in LDS; c in regs; W from L2.
// Hw scratch: per-wave [32 rows][144 shorts] (128 cols + 16 pad; 288B row
// stride = 8 dw mod 32 banks -> 4row x 8dw write pattern is conflict-free).
#define HL_OFF   32768
#define HL_PITCH 144
#define HW_WAVE  9216       // 32 * 144 * 2 bytes
#define DN_OFF   69632      // 32768 + 4*9216; [32][64] f32 dones slice
__global__ void __launch_bounds__(256, 1) persist32(
    const float* __restrict__ rnn, const float* __restrict__ dones,
    unsigned char* __restrict__ ws, float* __restrict__ out) {
  const unsigned short* whh = (const unsigned short*)(ws + F_WHH);
  const unsigned short* xproj = (const unsigned short*)(ws + F_XPROJ);

  __shared__ __align__(16) unsigned char smem[77824];
  float* dn_lds = (float*)(smem + DN_OFF);

  const int tid = threadIdx.x;
  const int w = tid >> 6, l = tid & 63;
  const int blk = (int)blockIdx.x;
  const int R0 = blk * 32;

  // ---- prologue: h0 A-frags -> LDS, dones -> LDS, c0 -> regs ----
  #pragma unroll
  for (int j = 0; j < 8; ++j) {
    int fa = w * 8 + j;                 // fa = mb*16 + ks
    int mb = fa >> 4, ks = fa & 15;
    int row = R0 + mb * 16 + (l & 15);
    int col = ks * 32 + ((l >> 4) << 3);
    const float* src = rnn + (size_t)row * 1024u + col;
    f32x4 a0 = *(const f32x4*)src, a1 = *(const f32x4*)(src + 4);
    u32x4 p;
    p.x = pack2(a0.x, a0.y); p.y = pack2(a0.z, a0.w);
    p.z = pack2(a1.x, a1.y); p.w = pack2(a1.z, a1.w);
    *(u32x4*)(smem + fa * 1024 + l * 16) = p;
  }
  #pragma unroll
  for (int j = 0; j < 2; ++j) {
    int chunk = w * 2 + j;
    gl_lds16(dones + (size_t)blk * 2048u + chunk * 256u + l * 4u,
             smem + DN_OFF + chunk * 1024);
  }
  f32x4 c[2][8];
  #pragma unroll
  for (int mb = 0; mb < 2; ++mb)
    #pragma unroll
    for (int nb = 0; nb < 8; ++nb)
      #pragma unroll
      for (int r = 0; r < 4; ++r) {
        int row = R0 + mb * 16 + ((l >> 4) << 2) + r;
        int hcol = w * 128 + nb * 16 + (l & 15);
        c[mb][nb][r] = rnn[(size_t)row * 1024u + 512u + hcol];
      }
  __syncthreads();

  unsigned short* Hw = (unsigned short*)(smem + HL_OFF + w * HW_WAVE);

  #pragma unroll 1
  for (int t = 0; t < 64; ++t) {
    // ---- xproj prefetch issued EARLY (latency hides under MFMA loop) ----
    u16x4 xq[2][4][8];
    #pragma unroll
    for (int mb = 0; mb < 2; ++mb)
      #pragma unroll
      for (int g = 0; g < 4; ++g)
        #pragma unroll
        for (int nb = 0; nb < 8; ++nb) {
          int n_abs = g * 32 + w * 8 + nb;
          xq[mb][g][nb] = __builtin_nontemporal_load((const u16x4*)(xproj +
              ((size_t)(t * 64 + blk * 2 + mb) * 128u + n_abs) * 256u + l * 4u));
        }

    // ---- gates = h @ W_hh^T : A from LDS, B streamed from L2 ----
    f32x4 acc[2][4][8];
    {
      f32x4 z = {0.f, 0.f, 0.f, 0.f};
      #pragma unroll
      for (int mb = 0; mb < 2; ++mb)
        #pragma unroll
        for (int g = 0; g < 4; ++g)
          #pragma unroll
          for (int nb = 0; nb < 8; ++nb) acc[mb][g][nb] = z;
    }
    #pragma unroll
    for (int kc = 0; kc < 16; ++kc) {
      s16x8 av0 = *(const s16x8*)(smem + kc * 1024 + l * 16);
      s16x8 av1 = *(const s16x8*)(smem + (16 + kc) * 1024 + l * 16);
      #pragma unroll
      for (int g = 0; g < 4; ++g)
        #pragma unroll
        for (int nb = 0; nb < 8; ++nb) {
          int n_abs = g * 32 + w * 8 + nb;
          s16x8 bv = *(const s16x8*)(whh + (size_t)(n_abs * 16 + kc) * 512u + l * 8u);
          acc[0][g][nb] = __builtin_amdgcn_mfma_f32_16x16x32_bf16(av0, bv, acc[0][g][nb], 0, 0, 0);
          acc[1][g][nb] = __builtin_amdgcn_mfma_f32_16x16x32_bf16(av1, bv, acc[1][g][nb], 0, 0, 0);
        }
    }

    // ---- LSTM cell: c in regs, h -> Hw scratch + nt outputs ----
    #pragma unroll
    for (int mb = 0; mb < 2; ++mb)
      #pragma unroll
      for (int nb = 0; nb < 8; ++nb)
        #pragma unroll
        for (int r = 0; r < 4; ++r) {
          float gi = sigm(acc[mb][0][nb][r] + bf2f(xq[mb][0][nb][r]));
          float gf = sigm(acc[mb][1][nb][r] + bf2f(xq[mb][1][nb][r]));
          float gg = tanhf(acc[mb][2][nb][r] + bf2f(xq[mb][2][nb][r]));
          float go = sigm(acc[mb][3][nb][r] + bf2f(xq[mb][3][nb][r]));
          float cc = gf * c[mb][nb][r] + gi * gg;
          float h = go * tanhf(cc);
          int lrow = mb * 16 + ((l >> 4) << 2) + r;
          float keep = 1.0f - dn_lds[lrow * 64 + t];   // next step's mask fold-in
          c[mb][nb][r] = cc * keep;
          Hw[lrow * HL_PITCH + nb * 16 + (l & 15)] = f2bf(h * keep);
          int b = R0 + lrow;
          int hcol = w * 128 + nb * 16 + (l & 15);
          __builtin_nontemporal_store(h, out + ((size_t)(b * 64 + t)) * 512u + hcol);
          __builtin_nontemporal_store(h, out + OUT_HS + ((size_t)(t * 1024 + b)) * 512u + hcol);
          __builtin_nontemporal_store(cc, out + OUT_CS + ((size_t)(t * 1024 + b)) * 512u + hcol);
          if (t == 63) {
            __builtin_nontemporal_store(h,  out + OUT_RNN + (size_t)b * 1024u + hcol);
            __builtin_nontemporal_store(cc, out + OUT_RNN + (size_t)b * 1024u + 512u + hcol);
          }
        }
    __syncthreads();   // all waves done reading old A-frags + Hw complete

    // ---- repack masked h: Hw scratch -> A-frags (wave-disjoint ks) ----
    #pragma unroll
    for (int mb = 0; mb < 2; ++mb)
      #pragma unroll
      for (int ksl = 0; ksl < 4; ++ksl) {
        int ks = w * 4 + ksl;   // global k-chunk; local col = ksl*32 + ...
        u32x4 hv = *(const u32x4*)(Hw + (size_t)(mb * 16 + (l & 15)) * HL_PITCH +
                                   ksl * 32 + ((l >> 4) << 3));
        *(u32x4*)(smem + (mb * 16 + ks) * 1024 + l * 16) = hv;
      }
    __syncthreads();   // A-frags ready for step t+1
  }
}

// ====================== FALLBACK (round-1, verified) ======================

__global__ void __launch_bounds__(256) prep_kernel(
    const float* __restrict__ rnn, const float* __restrict__ Wih,
    const float* __restrict__ Whh, const float* __restrict__ bih,
    const float* __restrict__ bhh, unsigned char* __restrict__ ws) {
  unsigned int tid = blockIdx.x * 256u + threadIdx.x;
  unsigned short* wcf = (unsigned short*)(ws + WC_OFF);
  unsigned short* hf  = (unsigned short*)(ws + HF_OFF);
  float* cf   = (float*)(ws + CF_OFF);
  float* bias = (float*)(ws + BIAS_OFF);
  if (tid < 262144u) {
    unsigned int frag = tid >> 6, l = tid & 63u;
    unsigned int cb = frag >> 5, ks = frag & 31u;
    unsigned int g  = cb * 16u + (l & 15u);
    unsigned int k0 = ks * 32u + ((l >> 4) << 3);
    const float* src = (k0 < 512u) ? (Wih + g * 512u + k0) : (Whh + g * 512u + (k0 - 512u));
    u32x4 p;
    p.x = pack2(src[0], src[1]); p.y = pack2(src[2], src[3]);
    p.z = pack2(src[4], src[5]); p.w = pack2(src[6], src[7]);
    *(u32x4*)(wcf + (size_t)frag * 512u + l * 8u) = p;
  } else if (tid < 327680u) {
    unsigned int t2 = tid - 262144u;
    unsigned int frag = t2 >> 6, l = t2 & 63u;
    unsigned int mb = frag >> 4, ks = frag & 15u;
    unsigned int b  = mb * 16u + (l & 15u);
    unsigned int c0 = ks * 32u + ((l >> 4) << 3);
    const float* src = rnn + (size_t)b * 1024u + c0;
    u32x4 p;
    p.x = pack2(src[0], src[1]); p.y = pack2(src[2], src[3]);
    p.z = pack2(src[4], src[5]); p.w = pack2(src[6], src[7]);
    *(u32x4*)(hf + (size_t)frag * 512u + l * 8u) = p;
  } else if (tid < 458752u) {
    unsigned int t2 = tid - 327680u;
    unsigned int frag = t2 >> 6, l = t2 & 63u;
    unsigned int mb = frag >> 5, cfi = frag & 31u;
    unsigned int hcol = cfi * 16u + (l & 15u);
    f32x4 p;
    #pragma unroll
    for (int r = 0; r < 4; ++r) {
      unsigned int b = mb * 16u + ((l >> 4) << 2) + r;
      p[r] = rnn[(size_t)b * 1024u + 512u + hcol];
    }
    *(f32x4*)(cf + (size_t)frag * 256u + l * 4u) = p;
  } else if (tid < 460800u) {
    unsigned int g = tid - 458752u;
    bias[g] = bih[g] + bhh[g];
  }
}

__global__ void __launch_bounds__(256) step_kernel(
    const float* __restrict__ xg, const float* __restrict__ dones,
    unsigned char* __restrict__ ws, float* __restrict__ out, int t) {
  const unsigned short* wcf = (const unsigned short*)(ws + WC_OFF);
  unsigned short* hf = (unsigned short*)(ws + HF_OFF);
  float* cf = (float*)(ws + CF_OFF);
  const float* bias = (const float*)(ws + BIAS_OFF);

  __shared__ __align__(16) unsigned char smem[49152];
  const int tid = threadIdx.x;
  const int w = tid >> 6, l = tid & 63;
  const int mh = w & 1, ch = w >> 1;
  const int mt = (int)blockIdx.x >> 4, ht = (int)blockIdx.x & 15;

  f32x4 acc[2][4];
  {
    f32x4 z = {0.f, 0.f, 0.f, 0.f};
    #pragma unroll
    for (int i = 0; i < 2; ++i)
      #pragma unroll
      for (int j = 0; j < 4; ++j) acc[i][j] = z;
  }

  f32x4 xv[2][2];

  auto stage_load = [&](int kc, int buf) {
    unsigned char* bb = smem + 16384 + buf * 16384;
    #pragma unroll
    for (int j = 0; j < 4; ++j) {
      int idx = w * 4 + j;
      int g = idx >> 2, cbl = (idx >> 1) & 1, ksl = idx & 1;
      int cb = g * 32 + ht * 2 + cbl;
      int ks = kc * 2 + ksl;
      const unsigned short* src = wcf + ((size_t)(cb * 32 + ks) * 64u + l) * 8u;
      gl_lds16(src, bb + idx * 1024);
    }
    unsigned char* ab = smem + buf * 8192;
    if (kc >= 8) {
      #pragma unroll
      for (int j = 0; j < 2; ++j) {
        int idx = w * 2 + j;
        int ksh = (kc - 8) * 2 + j;
        int mb_abs = mt * 4 + w;
        const unsigned short* src = hf + ((size_t)(mb_abs * 16 + ksh) * 64u + l) * 8u;
        gl_lds16(src, ab + idx * 1024);
      }
    } else {
      #pragma unroll
      for (int j = 0; j < 2; ++j) {
        int ks = kc * 2 + j;
        int b = mt * 64 + w * 16 + (l & 15);
        int k0 = ks * 32 + ((l >> 4) << 3);
        const float* src = xg + ((size_t)(b * 64 + t)) * 512u + k0;
        xv[j][0] = *(const f32x4*)src;
        xv[j][1] = *(const f32x4*)(src + 4);
      }
    }
  };
  auto stage_write = [&](int kc, int buf) {
    if (kc < 8) {
      unsigned char* ab = smem + buf * 8192;
      #pragma unroll
      for (int j = 0; j < 2; ++j) {
        int idx = w * 2 + j;
        u32x4 p;
        p.x = pack2(xv[j][0].x, xv[j][0].y); p.y = pack2(xv[j][0].z, xv[j][0].w);
        p.z = pack2(xv[j][1].x, xv[j][1].y); p.w = pack2(xv[j][1].z, xv[j][1].w);
        *(u32x4*)(ab + idx * 1024 + l * 16) = p;
      }
    }
  };

  stage_load(0, 0);
  stage_write(0, 0);
  __syncthreads();

  for (int kc = 0; kc < 16; ++kc) {
    int cur = kc & 1;
    if (kc < 15) stage_load(kc + 1, cur ^ 1);
    unsigned char* ab = smem + cur * 8192;
    unsigned char* bb = smem + 16384 + cur * 16384;
    s16x8 afr[2][2], bfr[4][2];
    #pragma unroll
    for (int mb2 = 0; mb2 < 2; ++mb2)
      #pragma unroll
      for (int ksl = 0; ksl < 2; ++ksl)
        afr[mb2][ksl] = *(const s16x8*)(ab + ((mh * 2 + mb2) * 2 + ksl) * 1024 + l * 16);
    #pragma unroll
    for (int g = 0; g < 4; ++g)
      #pragma unroll
      for (int ksl = 0; ksl < 2; ++ksl)
        bfr[g][ksl] = *(const s16x8*)(bb + (g * 4 + ch * 2 + ksl) * 1024 + l * 16);
    #pragma unroll
    for (int mb2 = 0; mb2 < 2; ++mb2)
      #pragma unroll
      for (int g = 0; g < 4; ++g)
        #pragma unroll
        for (int ksl = 0; ksl < 2; ++ksl)
          acc[mb2][g] = __builtin_amdgcn_mfma_f32_16x16x32_bf16(
              afr[mb2][ksl], bfr[g][ksl], acc[mb2][g], 0, 0, 0);
    if (kc < 15) stage_write(kc + 1, cur ^ 1);
    __syncthreads();
  }

  const int hcol = ht * 32 + ch * 16 + (l & 15);
  const float bi = bias[hcol], bf2 = bias[512 + hcol];
  const float bg = bias[1024 + hcol], bo = bias[1536 + hcol];
  float* Hl = (float*)smem;
  float* Cl = (float*)(smem + 9216);
  const int cfi = ht * 2 + ch;
  const int colL = ch * 16 + (l & 15);
  #pragma unroll
  for (int mb2 = 0; mb2 < 2; ++mb2) {
    const int mb_abs = mt * 4 + mh * 2 + mb2;
    const int fid = mb_abs * 32 + cfi;
    f32x4 cold = *(const f32x4*)(cf + (size_t)fid * 256u + l * 4u);
    f32x4 cmask;
    #pragma unroll
    for (int r = 0; r < 4; ++r) {
      float gi = sigm(acc[mb2][0][r] + bi);
      float gf = sigm(acc[mb2][1][r] + bf2);
      float gg = tanhf(acc[mb2][2][r] + bg);
      float go = sigm(acc[mb2][3][r] + bo);
      float c = gf * cold[r] + gi * gg;
      float h = go * tanhf(c);
      int brow = mb_abs * 16 + ((l >> 4) << 2) + r;
      float keep = 1.0f - dones[brow * 64 + t];
      cmask[r] = c * keep;
      int rowL = mh * 32 + mb2 * 16 + ((l >> 4) << 2) + r;
      Hl[rowL * 36 + colL] = h;
      Cl[rowL * 36 + colL] = c;
    }
    *(f32x4*)(cf + (size_t)fid * 256u + l * 4u) = cmask;
  }
  __syncthreads();

  {
    const int mb2f = tid >> 6, lp = tid & 63;
    const int mb_abs = mt * 4 + mb2f;
    const int rowL = mb2f * 16 + (lp & 15);
    const int c0 = (lp >> 4) << 3;
    const int brow = mt * 64 + rowL;
    const float keep = 1.0f - dones[brow * 64 + t];
    const float* hr = Hl + rowL * 36 + c0;
    u32x4 p;
    p.x = pack2(hr[0] * keep, hr[1] * keep);
    p.y = pack2(hr[2] * keep, hr[3] * keep);
    p.z = pack2(hr[4] * keep, hr[5] * keep);
    p.w = pack2(hr[6] * keep, hr[7] * keep);
    *(u32x4*)(hf + ((size_t)(mb_abs * 16 + ht) * 64u + lp) * 8u) = p;
  }
  {
    const int row = tid & 63, cg2 = tid >> 6;
    const int b = mt * 64 + row;
    const int c0 = cg2 * 8;
    const float* hr = Hl + row * 36 + c0;
    const float* cr = Cl + row * 36 + c0;
    f32x4 h0 = *(const f32x4*)hr,  h1 = *(const f32x4*)(hr + 4);
    f32x4 cc0 = *(const f32x4*)cr, cc1 = *(const f32x4*)(cr + 4);
    const int colg = ht * 32 + c0;
    size_t xoff = ((size_t)(b * 64 + t)) * 512u + colg;
    *(f32x4*)(out + xoff) = h0; *(f32x4*)(out + xoff + 4) = h1;
    size_t hoff = OUT_HS + ((size_t)(t * 1024 + b)) * 512u + colg;
    *(f32x4*)(out + hoff) = h0; *(f32x4*)(out + hoff + 4) = h1;
    size_t coff = OUT_CS + ((size_t)(t * 1024 + b)) * 512u + colg;
    *(f32x4*)(out + coff) = cc0; *(f32x4*)(out + coff + 4) = cc1;
    if (t == 63) {
      size_t roff = OUT_RNN + (size_t)b * 1024u + colg;
      *(f32x4*)(out + roff) = h0;        *(f32x4*)(out + roff + 4) = h1;
      *(f32x4*)(out + roff + 512) = cc0; *(f32x4*)(out + roff + 516) = cc1;
    }
  }
}

extern "C" void kernel_launch(void* const* d_in, const int* in_sizes, int n_in,
                              void* d_out, int out_size, void* d_ws, size_t ws_size,
                              hipStream_t stream) {
  const float* xg  = (const float*)d_in[0];
  const float* rnn = (const float*)d_in[1];
  const float* dn  = (const float*)d_in[2];
  const float* Wih = (const float*)d_in[3];
  const float* Whh = (const float*)d_in[4];
  const float* bih = (const float*)d_in[5];
  const float* bhh = (const float*)d_in[6];
  float* out = (float*)d_out;
  unsigned char* ws = (unsigned char*)d_ws;
  (void)in_sizes; (void)n_in; (void)out_size;

  if (ws_size >= (size_t)F_NEED) {
    prep_fast<<<17416, 256, 0, stream>>>(xg, Wih, Whh, bih, bhh, ws);
    gemm_xproj<<<8192, 256, 0, stream>>>(ws);
    persist32<<<32, 256, 0, stream>>>(rnn, dn, ws, out);
  } else {
    prep_kernel<<<1800, 256, 0, stream>>>(rnn, Wih, Whh, bih, bhh, ws);
    for (int t = 0; t < 64; ++t)
      step_kernel<<<256, 256, 0, stream>>>(xg, dn, ws, out, t);
  }
}

// Round 7
// 5682.353 us; speedup vs baseline: 1.2073x; 1.2073x over previous
//
#include <hip/hip_runtime.h>
#include <stdint.h>

// PolicyCoreRNN: LSTM, B=1024, T=64, H=I=512.
// Round 7: fix round-6 register-spill disaster. VALU-addressable VGPRs cap at
// 256 (512 is VGPR+AGPR combined) -> round-6's ~450-reg working set spilled
// to scratch (FETCH 2.4GB, 6.6ms). Same 32-block batch decomposition, but
// 512 threads (8 waves): per-wave acc[2][4][4]=128 regs, c[2][4]=32 regs,
// xproj folded transiently. W_hh read once per block per step from L2.

// ---------- round-1 (fallback) ws layout ----------
#define WC_OFF   0u
#define HF_OFF   4194304u
#define CF_OFF   5242880u
#define BIAS_OFF 7340032u
// ---------- fast-path ws layout (bytes) ----------
#define F_WIH   0u           // 2 MiB  bf16 W_ih frags (cb*16+ks)*1024
#define F_WHH   2097152u     // 2 MiB  bf16 W_hh frags
#define F_BIAS  6291456u     // 8 KiB  f32 b_ih+b_hh
#define F_XBF   7340032u     // 64 MiB bf16 x frags ((t*64+mb)*16+ks)*1024
#define F_XPROJ 74448896u    // 256 MiB bf16 x_proj D-frags ((t*64+mb)*128+n)*512
#define F_NEED  342884352u
// out (f32 elements): x | new_rnn_states | h_stack | c_stack
#define OUT_RNN  33554432u
#define OUT_HS   34603008u
#define OUT_CS   68157440u

typedef __attribute__((ext_vector_type(4))) float f32x4;
typedef __attribute__((ext_vector_type(8))) short s16x8;
typedef __attribute__((ext_vector_type(4))) unsigned int u32x4;
typedef __attribute__((ext_vector_type(4))) unsigned short u16x4;

__device__ __forceinline__ unsigned short f2bf(float f) {
  union { float f; unsigned int u; } v; v.f = f;
  return (unsigned short)((v.u + 0x7FFFu + ((v.u >> 16) & 1u)) >> 16);
}
__device__ __forceinline__ float bf2f(unsigned short s) {
  union { unsigned int u; float f; } v; v.u = ((unsigned int)s) << 16;
  return v.f;
}
__device__ __forceinline__ unsigned int pack2(float a, float b) {
  return (unsigned int)f2bf(a) | ((unsigned int)f2bf(b) << 16);
}
__device__ __forceinline__ float sigm(float x) { return 1.0f / (1.0f + __expf(-x)); }

__device__ __forceinline__ void gl_lds16(const void* g, void* lds) {
  __builtin_amdgcn_global_load_lds(
      (const __attribute__((address_space(1))) unsigned int*)g,
      (__attribute__((address_space(3))) unsigned int*)lds, 16, 0, 0);
}

// Fragment conventions (16x16x32 bf16 MFMA):
//  A/B input frag (1KB): lane l holds index (l&15) of the 16-dim, k = ks*32+(l>>4)*8+e.
//  D frag: col = l&15 (B dim), row = (l>>4)*4 + reg (A dim).  [m89-verified]

// ====================== FAST PATH ======================

__global__ void __launch_bounds__(256) prep_fast(
    const float* __restrict__ xg, const float* __restrict__ Wih,
    const float* __restrict__ Whh, const float* __restrict__ bih,
    const float* __restrict__ bhh, unsigned char* __restrict__ ws) {
  unsigned int tid = blockIdx.x * 256u + threadIdx.x;
  unsigned short* wih_f = (unsigned short*)(ws + F_WIH);
  unsigned short* whh_f = (unsigned short*)(ws + F_WHH);
  float* bias = (float*)(ws + F_BIAS);
  unsigned short* xbf = (unsigned short*)(ws + F_XBF);
  if (tid < 131072u) {
    unsigned int frag = tid >> 6, l = tid & 63u;
    unsigned int cb = frag >> 4, ks = frag & 15u;
    unsigned int g  = cb * 16u + (l & 15u);
    unsigned int k0 = ks * 32u + ((l >> 4) << 3);
    const float* src = Wih + (size_t)g * 512u + k0;
    u32x4 p;
    p.x = pack2(src[0], src[1]); p.y = pack2(src[2], src[3]);
    p.z = pack2(src[4], src[5]); p.w = pack2(src[6], src[7]);
    *(u32x4*)(wih_f + (size_t)frag * 512u + l * 8u) = p;
  } else if (tid < 262144u) {
    unsigned int t2 = tid - 131072u;
    unsigned int frag = t2 >> 6, l = t2 & 63u;
    unsigned int cb = frag >> 4, ks = frag & 15u;
    unsigned int g  = cb * 16u + (l & 15u);
    unsigned int k0 = ks * 32u + ((l >> 4) << 3);
    const float* src = Whh + (size_t)g * 512u + k0;
    u32x4 p;
    p.x = pack2(src[0], src[1]); p.y = pack2(src[2], src[3]);
    p.z = pack2(src[4], src[5]); p.w = pack2(src[6], src[7]);
    *(u32x4*)(whh_f + (size_t)frag * 512u + l * 8u) = p;
  } else if (tid < 264192u) {
    unsigned int g = tid - 262144u;
    bias[g] = bih[g] + bhh[g];
  } else if (tid < 4458496u) {
    unsigned int t2 = tid - 264192u;
    unsigned int frag = t2 >> 6, l = t2 & 63u;
    unsigned int ks = frag & 15u, mb = (frag >> 4) & 63u, t = frag >> 10;
    unsigned int b  = mb * 16u + (l & 15u);
    unsigned int k0 = ks * 32u + ((l >> 4) << 3);
    const float* src = xg + ((size_t)(b * 64u + t)) * 512u + k0;
    u32x4 p;
    p.x = pack2(src[0], src[1]); p.y = pack2(src[2], src[3]);
    p.z = pack2(src[4], src[5]); p.w = pack2(src[6], src[7]);
    *(u32x4*)(xbf + (size_t)frag * 512u + l * 8u) = p;
  }
}

// Big GEMM: x_proj[t] = x_t @ W_ih^T + bias, bf16 D-frag output.
// grid 8192 = t(64) x mtile(8) x ntile(16); tile 128M x 128N, K=512, BK=64.
__global__ void __launch_bounds__(256) gemm_xproj(unsigned char* __restrict__ ws) {
  const unsigned short* xbf = (const unsigned short*)(ws + F_XBF);
  const unsigned short* wih = (const unsigned short*)(ws + F_WIH);
  const float* bias = (const float*)(ws + F_BIAS);
  unsigned short* xproj = (unsigned short*)(ws + F_XPROJ);

  __shared__ __align__(16) unsigned char smem[65536];
  const int tid = threadIdx.x;
  const int w = tid >> 6, l = tid & 63;
  const int mh = w & 1, nh = w >> 1;
  const int bid = blockIdx.x;
  const int t = bid >> 7, mtile = (bid >> 4) & 7, ntile = bid & 15;

  f32x4 acc[4][4];
  {
    f32x4 z = {0.f, 0.f, 0.f, 0.f};
    #pragma unroll
    for (int i = 0; i < 4; ++i)
      #pragma unroll
      for (int j = 0; j < 4; ++j) acc[i][j] = z;
  }

  auto stage = [&](int kc, int buf) {
    unsigned char* ab = smem + buf * 16384;
    unsigned char* bb = smem + 32768 + buf * 16384;
    #pragma unroll
    for (int j = 0; j < 4; ++j) {
      int idx = w * 4 + j;
      int mb_l = idx >> 1, ksl = idx & 1;
      size_t frag = (size_t)(t * 64 + mtile * 8 + mb_l) * 16u + kc * 2 + ksl;
      gl_lds16(xbf + (frag * 64u + l) * 8u, ab + idx * 1024);
    }
    #pragma unroll
    for (int j = 0; j < 4; ++j) {
      int idx = w * 4 + j;
      int cb_l = idx >> 1, ksl = idx & 1;
      size_t frag = (size_t)(ntile * 8 + cb_l) * 16u + kc * 2 + ksl;
      gl_lds16(wih + (frag * 64u + l) * 8u, bb + idx * 1024);
    }
  };

  stage(0, 0);
  __syncthreads();
  for (int kc = 0; kc < 8; ++kc) {
    int cur = kc & 1;
    if (kc < 7) stage(kc + 1, cur ^ 1);
    unsigned char* ab = smem + cur * 16384;
    unsigned char* bb = smem + 32768 + cur * 16384;
    s16x8 afr[4][2], bfr[4][2];
    #pragma unroll
    for (int m = 0; m < 4; ++m)
      #pragma unroll
      for (int ksl = 0; ksl < 2; ++ksl)
        afr[m][ksl] = *(const s16x8*)(ab + ((mh * 4 + m) * 2 + ksl) * 1024 + l * 16);
    #pragma unroll
    for (int n = 0; n < 4; ++n)
      #pragma unroll
      for (int ksl = 0; ksl < 2; ++ksl)
        bfr[n][ksl] = *(const s16x8*)(bb + ((nh * 4 + n) * 2 + ksl) * 1024 + l * 16);
    #pragma unroll
    for (int m = 0; m < 4; ++m)
      #pragma unroll
      for (int n = 0; n < 4; ++n)
        #pragma unroll
        for (int ksl = 0; ksl < 2; ++ksl)
          acc[m][n] = __builtin_amdgcn_mfma_f32_16x16x32_bf16(
              afr[m][ksl], bfr[n][ksl], acc[m][n], 0, 0, 0);
    __syncthreads();
  }

  #pragma unroll
  for (int m = 0; m < 4; ++m) {
    int mb_abs = mtile * 8 + mh * 4 + m;
    #pragma unroll
    for (int n = 0; n < 4; ++n) {
      int n_abs = ntile * 8 + nh * 4 + n;
      float bc = bias[n_abs * 16 + (l & 15)];
      u16x4 p;
      #pragma unroll
      for (int r = 0; r < 4; ++r) p[r] = f2bf(acc[m][n][r] + bc);
      *(u16x4*)(xproj + ((size_t)(t * 64 + mb_abs) * 128u + n_abs) * 256u + l * 4u) = p;
    }
  }
}

// Persistent batch-decomposed recurrence: 32 blocks x 512 threads (8 waves).
// Block owns rows [blk*32, blk*32+32), ALL 512 h-cols (LDS-local recurrence,
// no grid sync). Wave w owns hcols [w*64, (w+1)*64): acc[2][4][4]=128 regs,
// c[2][4]=32 regs. W_hh streamed from L2 once per block per step (2MB).
// Hw: per-wave [32 rows][80 shorts] (64 cols + pad; 160B stride, 16B-aligned).
#define HL_OFF   32768
#define HL_PITCH 80
#define HW_WAVE  5120       // 32*80*2
#define DN_OFF   73728      // 32768 + 8*5120; [32][64] f32 dones slice
__global__ void __launch_bounds__(512, 2) persist512(
    const float* __restrict__ rnn, const float* __restrict__ dones,
    unsigned char* __restrict__ ws, float* __restrict__ out) {
  const unsigned short* whh = (const unsigned short*)(ws + F_WHH);
  const unsigned short* xproj = (const unsigned short*)(ws + F_XPROJ);

  __shared__ __align__(16) unsigned char smem[81920];
  float* dn_lds = (float*)(smem + DN_OFF);

  const int tid = threadIdx.x;
  const int w = tid >> 6, l = tid & 63;   // w < 8
  const int blk = (int)blockIdx.x;
  const int R0 = blk * 32;

  // ---- prologue: h0 A-frags -> LDS, dones -> LDS, c0 -> regs ----
  #pragma unroll
  for (int j = 0; j < 4; ++j) {
    int fa = w * 4 + j;                 // fa = mb*16 + ks
    int mb = fa >> 4, ks = fa & 15;
    int row = R0 + mb * 16 + (l & 15);
    int col = ks * 32 + ((l >> 4) << 3);
    const float* src = rnn + (size_t)row * 1024u + col;
    f32x4 a0 = *(const f32x4*)src, a1 = *(const f32x4*)(src + 4);
    u32x4 p;
    p.x = pack2(a0.x, a0.y); p.y = pack2(a0.z, a0.w);
    p.z = pack2(a1.x, a1.y); p.w = pack2(a1.z, a1.w);
    *(u32x4*)(smem + fa * 1024 + l * 16) = p;
  }
  gl_lds16(dones + (size_t)blk * 2048u + w * 256u + l * 4u,
           smem + DN_OFF + w * 1024);
  f32x4 c[2][4];
  #pragma unroll
  for (int mb = 0; mb < 2; ++mb)
    #pragma unroll
    for (int nb = 0; nb < 4; ++nb)
      #pragma unroll
      for (int r = 0; r < 4; ++r) {
        int row = R0 + mb * 16 + ((l >> 4) << 2) + r;
        int hcol = w * 64 + nb * 16 + (l & 15);
        c[mb][nb][r] = rnn[(size_t)row * 1024u + 512u + hcol];
      }
  __syncthreads();

  unsigned short* Hw = (unsigned short*)(smem + HL_OFF + w * HW_WAVE);

  #pragma unroll 1
  for (int t = 0; t < 64; ++t) {
    // ---- gates = h @ W_hh^T : A from LDS, B streamed from L2 ----
    f32x4 acc[2][4][4];
    {
      f32x4 z = {0.f, 0.f, 0.f, 0.f};
      #pragma unroll
      for (int mb = 0; mb < 2; ++mb)
        #pragma unroll
        for (int g = 0; g < 4; ++g)
          #pragma unroll
          for (int nb = 0; nb < 4; ++nb) acc[mb][g][nb] = z;
    }
    #pragma unroll
    for (int kc = 0; kc < 16; ++kc) {
      s16x8 av0 = *(const s16x8*)(smem + kc * 1024 + l * 16);
      s16x8 av1 = *(const s16x8*)(smem + (16 + kc) * 1024 + l * 16);
      #pragma unroll
      for (int g = 0; g < 4; ++g)
        #pragma unroll
        for (int nb = 0; nb < 4; ++nb) {
          int n_abs = g * 32 + w * 4 + nb;
          s16x8 bv = *(const s16x8*)(whh + (size_t)(n_abs * 16 + kc) * 512u + l * 8u);
          acc[0][g][nb] = __builtin_amdgcn_mfma_f32_16x16x32_bf16(av0, bv, acc[0][g][nb], 0, 0, 0);
          acc[1][g][nb] = __builtin_amdgcn_mfma_f32_16x16x32_bf16(av1, bv, acc[1][g][nb], 0, 0, 0);
        }
    }

    // ---- fold xproj into acc (transient loads; bias already folded) ----
    #pragma unroll
    for (int mb = 0; mb < 2; ++mb)
      #pragma unroll
      for (int g = 0; g < 4; ++g)
        #pragma unroll
        for (int nb = 0; nb < 4; ++nb) {
          int n_abs = g * 32 + w * 4 + nb;
          u16x4 xv = __builtin_nontemporal_load((const u16x4*)(xproj +
              ((size_t)(t * 64 + blk * 2 + mb) * 128u + n_abs) * 256u + l * 4u));
          #pragma unroll
          for (int r = 0; r < 4; ++r) acc[mb][g][nb][r] += bf2f(xv[r]);
        }

    // ---- LSTM cell: c in regs, h -> Hw scratch + nt outputs ----
    #pragma unroll
    for (int mb = 0; mb < 2; ++mb)
      #pragma unroll
      for (int nb = 0; nb < 4; ++nb)
        #pragma unroll
        for (int r = 0; r < 4; ++r) {
          float gi = sigm(acc[mb][0][nb][r]);
          float gf = sigm(acc[mb][1][nb][r]);
          float gg = tanhf(acc[mb][2][nb][r]);
          float go = sigm(acc[mb][3][nb][r]);
          float cc = gf * c[mb][nb][r] + gi * gg;
          float h = go * tanhf(cc);
          int lrow = mb * 16 + ((l >> 4) << 2) + r;
          float keep = 1.0f - dn_lds[lrow * 64 + t];   // next step's mask fold-in
          c[mb][nb][r] = cc * keep;
          Hw[lrow * HL_PITCH + nb * 16 + (l & 15)] = f2bf(h * keep);
          int b = R0 + lrow;
          int hcol = w * 64 + nb * 16 + (l & 15);
          __builtin_nontemporal_store(h, out + ((size_t)(b * 64 + t)) * 512u + hcol);
          __builtin_nontemporal_store(h, out + OUT_HS + ((size_t)(t * 1024 + b)) * 512u + hcol);
          __builtin_nontemporal_store(cc, out + OUT_CS + ((size_t)(t * 1024 + b)) * 512u + hcol);
          if (t == 63) {
            __builtin_nontemporal_store(h,  out + OUT_RNN + (size_t)b * 1024u + hcol);
            __builtin_nontemporal_store(cc, out + OUT_RNN + (size_t)b * 1024u + 512u + hcol);
          }
        }
    __syncthreads();   // all waves done reading old A-frags; Hw complete

    // ---- repack masked h: own Hw -> A-frags ks = {2w, 2w+1} ----
    #pragma unroll
    for (int mb = 0; mb < 2; ++mb)
      #pragma unroll
      for (int j = 0; j < 2; ++j) {
        int ks = w * 2 + j;
        u32x4 hv = *(const u32x4*)(Hw + (size_t)(mb * 16 + (l & 15)) * HL_PITCH +
                                   j * 32 + ((l >> 4) << 3));
        *(u32x4*)(smem + (mb * 16 + ks) * 1024 + l * 16) = hv;
      }
    __syncthreads();   // A-frags ready for step t+1
  }
}

// ====================== FALLBACK (round-1, verified) ======================

__global__ void __launch_bounds__(256) prep_kernel(
    const float* __restrict__ rnn, const float* __restrict__ Wih,
    const float* __restrict__ Whh, const float* __restrict__ bih,
    const float* __restrict__ bhh, unsigned char* __restrict__ ws) {
  unsigned int tid = blockIdx.x * 256u + threadIdx.x;
  unsigned short* wcf = (unsigned short*)(ws + WC_OFF);
  unsigned short* hf  = (unsigned short*)(ws + HF_OFF);
  float* cf   = (float*)(ws + CF_OFF);
  float* bias = (float*)(ws + BIAS_OFF);
  if (tid < 262144u) {
    unsigned int frag = tid >> 6, l = tid & 63u;
    unsigned int cb = frag >> 5, ks = frag & 31u;
    unsigned int g  = cb * 16u + (l & 15u);
    unsigned int k0 = ks * 32u + ((l >> 4) << 3);
    const float* src = (k0 < 512u) ? (Wih + g * 512u + k0) : (Whh + g * 512u + (k0 - 512u));
    u32x4 p;
    p.x = pack2(src[0], src[1]); p.y = pack2(src[2], src[3]);
    p.z = pack2(src[4], src[5]); p.w = pack2(src[6], src[7]);
    *(u32x4*)(wcf + (size_t)frag * 512u + l * 8u) = p;
  } else if (tid < 327680u) {
    unsigned int t2 = tid - 262144u;
    unsigned int frag = t2 >> 6, l = t2 & 63u;
    unsigned int mb = frag >> 4, ks = frag & 15u;
    unsigned int b  = mb * 16u + (l & 15u);
    unsigned int c0 = ks * 32u + ((l >> 4) << 3);
    const float* src = rnn + (size_t)b * 1024u + c0;
    u32x4 p;
    p.x = pack2(src[0], src[1]); p.y = pack2(src[2], src[3]);
    p.z = pack2(src[4], src[5]); p.w = pack2(src[6], src[7]);
    *(u32x4*)(hf + (size_t)frag * 512u + l * 8u) = p;
  } else if (tid < 458752u) {
    unsigned int t2 = tid - 327680u;
    unsigned int frag = t2 >> 6, l = t2 & 63u;
    unsigned int mb = frag >> 5, cfi = frag & 31u;
    unsigned int hcol = cfi * 16u + (l & 15u);
    f32x4 p;
    #pragma unroll
    for (int r = 0; r < 4; ++r) {
      unsigned int b = mb * 16u + ((l >> 4) << 2) + r;
      p[r] = rnn[(size_t)b * 1024u + 512u + hcol];
    }
    *(f32x4*)(cf + (size_t)frag * 256u + l * 4u) = p;
  } else if (tid < 460800u) {
    unsigned int g = tid - 458752u;
    bias[g] = bih[g] + bhh[g];
  }
}

__global__ void __launch_bounds__(256) step_kernel(
    const float* __restrict__ xg, const float* __restrict__ dones,
    unsigned char* __restrict__ ws, float* __restrict__ out, int t) {
  const unsigned short* wcf = (const unsigned short*)(ws + WC_OFF);
  unsigned short* hf = (unsigned short*)(ws + HF_OFF);
  float* cf = (float*)(ws + CF_OFF);
  const float* bias = (const float*)(ws + BIAS_OFF);

  __shared__ __align__(16) unsigned char smem[49152];
  const int tid = threadIdx.x;
  const int w = tid >> 6, l = tid & 63;
  const int mh = w & 1, ch = w >> 1;
  const int mt = (int)blockIdx.x >> 4, ht = (int)blockIdx.x & 15;

  f32x4 acc[2][4];
  {
    f32x4 z = {0.f, 0.f, 0.f, 0.f};
    #pragma unroll
    for (int i = 0; i < 2; ++i)
      #pragma unroll
      for (int j = 0; j < 4; ++j) acc[i][j] = z;
  }

  f32x4 xv[2][2];

  auto stage_load = [&](int kc, int buf) {
    unsigned char* bb = smem + 16384 + buf * 16384;
    #pragma unroll
    for (int j = 0; j < 4; ++j) {
      int idx = w * 4 + j;
      int g = idx >> 2, cbl = (idx >> 1) & 1, ksl = idx & 1;
      int cb = g * 32 + ht * 2 + cbl;
      int ks = kc * 2 + ksl;
      const unsigned short* src = wcf + ((size_t)(cb * 32 + ks) * 64u + l) * 8u;
      gl_lds16(src, bb + idx * 1024);
    }
    unsigned char* ab = smem + buf * 8192;
    if (kc >= 8) {
      #pragma unroll
      for (int j = 0; j < 2; ++j) {
        int idx = w * 2 + j;
        int ksh = (kc - 8) * 2 + j;
        int mb_abs = mt * 4 + w;
        const unsigned short* src = hf + ((size_t)(mb_abs * 16 + ksh) * 64u + l) * 8u;
        gl_lds16(src, ab + idx * 1024);
      }
    } else {
      #pragma unroll
      for (int j = 0; j < 2; ++j) {
        int ks = kc * 2 + j;
        int b = mt * 64 + w * 16 + (l & 15);
        int k0 = ks * 32 + ((l >> 4) << 3);
        const float* src = xg + ((size_t)(b * 64 + t)) * 512u + k0;
        xv[j][0] = *(const f32x4*)src;
        xv[j][1] = *(const f32x4*)(src + 4);
      }
    }
  };
  auto stage_write = [&](int kc, int buf) {
    if (kc < 8) {
      unsigned char* ab = smem + buf * 8192;
      #pragma unroll
      for (int j = 0; j < 2; ++j) {
        int idx = w * 2 + j;
        u32x4 p;
        p.x = pack2(xv[j][0].x, xv[j][0].y); p.y = pack2(xv[j][0].z, xv[j][0].w);
        p.z = pack2(xv[j][1].x, xv[j][1].y); p.w = pack2(xv[j][1].z, xv[j][1].w);
        *(u32x4*)(ab + idx * 1024 + l * 16) = p;
      }
    }
  };

  stage_load(0, 0);
  stage_write(0, 0);
  __syncthreads();

  for (int kc = 0; kc < 16; ++kc) {
    int cur = kc & 1;
    if (kc < 15) stage_load(kc + 1, cur ^ 1);
    unsigned char* ab = smem + cur * 8192;
    unsigned char* bb = smem + 16384 + cur * 16384;
    s16x8 afr[2][2], bfr[4][2];
    #pragma unroll
    for (int mb2 = 0; mb2 < 2; ++mb2)
      #pragma unroll
      for (int ksl = 0; ksl < 2; ++ksl)
        afr[mb2][ksl] = *(const s16x8*)(ab + ((mh * 2 + mb2) * 2 + ksl) * 1024 + l * 16);
    #pragma unroll
    for (int g = 0; g < 4; ++g)
      #pragma unroll
      for (int ksl = 0; ksl < 2; ++ksl)
        bfr[g][ksl] = *(const s16x8*)(bb + (g * 4 + ch * 2 + ksl) * 1024 + l * 16);
    #pragma unroll
    for (int mb2 = 0; mb2 < 2; ++mb2)
      #pragma unroll
      for (int g = 0; g < 4; ++g)
        #pragma unroll
        for (int ksl = 0; ksl < 2; ++ksl)
          acc[mb2][g] = __builtin_amdgcn_mfma_f32_16x16x32_bf16(
              afr[mb2][ksl], bfr[g][ksl], acc[mb2][g], 0, 0, 0);
    if (kc < 15) stage_write(kc + 1, cur ^ 1);
    __syncthreads();
  }

  const int hcol = ht * 32 + ch * 16 + (l & 15);
  const float bi = bias[hcol], bf2 = bias[512 + hcol];
  const float bg = bias[1024 + hcol], bo = bias[1536 + hcol];
  float* Hl = (float*)smem;
  float* Cl = (float*)(smem + 9216);
  const int cfi = ht * 2 + ch;
  const int colL = ch * 16 + (l & 15);
  #pragma unroll
  for (int mb2 = 0; mb2 < 2; ++mb2) {
    const int mb_abs = mt * 4 + mh * 2 + mb2;
    const int fid = mb_abs * 32 + cfi;
    f32x4 cold = *(const f32x4*)(cf + (size_t)fid * 256u + l * 4u);
    f32x4 cmask;
    #pragma unroll
    for (int r = 0; r < 4; ++r) {
      float gi = sigm(acc[mb2][0][r] + bi);
      float gf = sigm(acc[mb2][1][r] + bf2);
      float gg = tanhf(acc[mb2][2][r] + bg);
      float go = sigm(acc[mb2][3][r] + bo);
      float c = gf * cold[r] + gi * gg;
      float h = go * tanhf(c);
      int brow = mb_abs * 16 + ((l >> 4) << 2) + r;
      float keep = 1.0f - dones[brow * 64 + t];
      cmask[r] = c * keep;
      int rowL = mh * 32 + mb2 * 16 + ((l >> 4) << 2) + r;
      Hl[rowL * 36 + colL] = h;
      Cl[rowL * 36 + colL] = c;
    }
    *(f32x4*)(cf + (size_t)fid * 256u + l * 4u) = cmask;
  }
  __syncthreads();

  {
    const int mb2f = tid >> 6, lp = tid & 63;
    const int mb_abs = mt * 4 + mb2f;
    const int rowL = mb2f * 16 + (lp & 15);
    const int c0 = (lp >> 4) << 3;
    const int brow = mt * 64 + rowL;
    const float keep = 1.0f - dones[brow * 64 + t];
    const float* hr = Hl + rowL * 36 + c0;
    u32x4 p;
    p.x = pack2(hr[0] * keep, hr[1] * keep);
    p.y = pack2(hr[2] * keep, hr[3] * keep);
    p.z = pack2(hr[4] * keep, hr[5] * keep);
    p.w = pack2(hr[6] * keep, hr[7] * keep);
    *(u32x4*)(hf + ((size_t)(mb_abs * 16 + ht) * 64u + lp) * 8u) = p;
  }
  {
    const int row = tid & 63, cg2 = tid >> 6;
    const int b = mt * 64 + row;
    const int c0 = cg2 * 8;
    const float* hr = Hl + row * 36 + c0;
    const float* cr = Cl + row * 36 + c0;
    f32x4 h0 = *(const f32x4*)hr,  h1 = *(const f32x4*)(hr + 4);
    f32x4 cc0 = *(const f32x4*)cr, cc1 = *(const f32x4*)(cr + 4);
    const int colg = ht * 32 + c0;
    size_t xoff = ((size_t)(b * 64 + t)) * 512u + colg;
    *(f32x4*)(out + xoff) = h0; *(f32x4*)(out + xoff + 4) = h1;
    size_t hoff = OUT_HS + ((size_t)(t * 1024 + b)) * 512u + colg;
    *(f32x4*)(out + hoff) = h0; *(f32x4*)(out + hoff + 4) = h1;
    size_t coff = OUT_CS + ((size_t)(t * 1024 + b)) * 512u + colg;
    *(f32x4*)(out + coff) = cc0; *(f32x4*)(out + coff + 4) = cc1;
    if (t == 63) {
      size_t roff = OUT_RNN + (size_t)b * 1024u + colg;
      *(f32x4*)(out + roff) = h0;        *(f32x4*)(out + roff + 4) = h1;
      *(f32x4*)(out + roff + 512) = cc0; *(f32x4*)(out + roff + 516) = cc1;
    }
  }
}

extern "C" void kernel_launch(void* const* d_in, const int* in_sizes, int n_in,
                              void* d_out, int out_size, void* d_ws, size_t ws_size,
                              hipStream_t stream) {
  const float* xg  = (const float*)d_in[0];
  const float* rnn = (const float*)d_in[1];
  const float* dn  = (const float*)d_in[2];
  const float* Wih = (const float*)d_in[3];
  const float* Whh = (const float*)d_in[4];
  const float* bih = (const float*)d_in[5];
  const float* bhh = (const float*)d_in[6];
  float* out = (float*)d_out;
  unsigned char* ws = (unsigned char*)d_ws;
  (void)in_sizes; (void)n_in; (void)out_size;

  if (ws_size >= (size_t)F_NEED) {
    prep_fast<<<17416, 256, 0, stream>>>(xg, Wih, Whh, bih, bhh, ws);
    gemm_xproj<<<8192, 256, 0, stream>>>(ws);
    persist512<<<32, 512, 0, stream>>>(rnn, dn, ws, out);
  } else {
    prep_kernel<<<1800, 256, 0, stream>>>(rnn, Wih, Whh, bih, bhh, ws);
    for (int t = 0; t < 64; ++t)
      step_kernel<<<256, 256, 0, stream>>>(xg, dn, ws, out, t);
  }
}

// Round 8
// 2223.725 us; speedup vs baseline: 3.0850x; 2.5553x over previous
//
#include <hip/hip_runtime.h>
#include <stdint.h>

// PolicyCoreRNN: LSTM, B=1024, T=64, H=I=512.
// Round 8: 256-block persistent recurrence with software spin barrier
// (plain launch -> graph-capture safe, unlike hipLaunchCooperativeKernel).
// Column+row tiling as round 3: block (mt,ht) owns 64 rows x 32 h-cols,
// W slice (128KB) in LDS staged ONCE for all 64 steps; c in regs; dones in
// LDS. Cross-block h exchange via AGENT-SCOPE atomics (coherence point, G16)
// with double-buffered h-frag buffers; one barrier per step.

// ---------- round-1 (fallback) ws layout ----------
#define WC_OFF   0u
#define HF_OFF   4194304u
#define CF_OFF   5242880u
#define BIAS_OFF 7340032u
// ---------- fast-path ws layout (bytes) ----------
#define F_WIH   0u           // 2 MiB  bf16 W_ih frags (cb*16+ks)*1024
#define F_WHH   2097152u     // 2 MiB  bf16 W_hh frags
#define F_HF0   4194304u     // 1 MiB  bf16 h-state frags buf0 (mb*16+ks)*1024
#define F_HF1   5242880u     // 1 MiB  bf16 h-state frags buf1
#define F_BIAS  6291456u     // 8 KiB  f32 b_ih+b_hh
#define F_CTR   6299648u     // 4 B    barrier counter
#define F_XBF   7340032u     // 64 MiB bf16 x frags ((t*64+mb)*16+ks)*1024
#define F_XPROJ 74448896u    // 256 MiB bf16 x_proj D-frags ((t*64+mb)*128+n)*512
#define F_NEED  342884352u
// out (f32 elements): x | new_rnn_states | h_stack | c_stack
#define OUT_RNN  33554432u
#define OUT_HS   34603008u
#define OUT_CS   68157440u

typedef __attribute__((ext_vector_type(4))) float f32x4;
typedef __attribute__((ext_vector_type(8))) short s16x8;
typedef __attribute__((ext_vector_type(4))) unsigned int u32x4;
typedef __attribute__((ext_vector_type(4))) unsigned short u16x4;

__device__ __forceinline__ unsigned short f2bf(float f) {
  union { float f; unsigned int u; } v; v.f = f;
  return (unsigned short)((v.u + 0x7FFFu + ((v.u >> 16) & 1u)) >> 16);
}
__device__ __forceinline__ float bf2f(unsigned short s) {
  union { unsigned int u; float f; } v; v.u = ((unsigned int)s) << 16;
  return v.f;
}
__device__ __forceinline__ unsigned int pack2(float a, float b) {
  return (unsigned int)f2bf(a) | ((unsigned int)f2bf(b) << 16);
}
__device__ __forceinline__ float sigm(float x) { return 1.0f / (1.0f + __expf(-x)); }

__device__ __forceinline__ void gl_lds16(const void* g, void* lds) {
  __builtin_amdgcn_global_load_lds(
      (const __attribute__((address_space(1))) unsigned int*)g,
      (__attribute__((address_space(3))) unsigned int*)lds, 16, 0, 0);
}

// agent-scope (device-coherent) 16B load/store as 2x u64 atomics
__device__ __forceinline__ s16x8 aload16(const unsigned short* p) {
  union { unsigned long long q[2]; s16x8 v; } u;
  u.q[0] = __hip_atomic_load((const unsigned long long*)p,
                             __ATOMIC_RELAXED, __HIP_MEMORY_SCOPE_AGENT);
  u.q[1] = __hip_atomic_load((const unsigned long long*)(p + 4),
                             __ATOMIC_RELAXED, __HIP_MEMORY_SCOPE_AGENT);
  return u.v;
}
__device__ __forceinline__ void astore16(unsigned short* p, u32x4 v) {
  union { u32x4 v; unsigned long long q[2]; } u; u.v = v;
  __hip_atomic_store((unsigned long long*)p, u.q[0],
                     __ATOMIC_RELAXED, __HIP_MEMORY_SCOPE_AGENT);
  __hip_atomic_store((unsigned long long*)(p + 4), u.q[1],
                     __ATOMIC_RELAXED, __HIP_MEMORY_SCOPE_AGENT);
}

// Fragment conventions (16x16x32 bf16 MFMA):
//  A/B input frag (1KB): lane l holds index (l&15) of the 16-dim, k = ks*32+(l>>4)*8+e.
//  D frag: col = l&15 (B dim), row = (l>>4)*4 + reg (A dim).  [m89-verified]

// ====================== FAST PATH ======================

__global__ void __launch_bounds__(256) prep_fast(
    const float* __restrict__ xg, const float* __restrict__ rnn,
    const float* __restrict__ Wih, const float* __restrict__ Whh,
    const float* __restrict__ bih, const float* __restrict__ bhh,
    unsigned char* __restrict__ ws) {
  unsigned int tid = blockIdx.x * 256u + threadIdx.x;
  unsigned short* wih_f = (unsigned short*)(ws + F_WIH);
  unsigned short* whh_f = (unsigned short*)(ws + F_WHH);
  unsigned short* hf    = (unsigned short*)(ws + F_HF0);
  float* bias = (float*)(ws + F_BIAS);
  unsigned short* xbf = (unsigned short*)(ws + F_XBF);
  if (tid < 131072u) {
    // W_ih frags: frag=(cb<128, ks<16); col=cb*16+(l&15); k0=ks*32+(l>>4)*8
    unsigned int frag = tid >> 6, l = tid & 63u;
    unsigned int cb = frag >> 4, ks = frag & 15u;
    unsigned int g  = cb * 16u + (l & 15u);
    unsigned int k0 = ks * 32u + ((l >> 4) << 3);
    const float* src = Wih + (size_t)g * 512u + k0;
    u32x4 p;
    p.x = pack2(src[0], src[1]); p.y = pack2(src[2], src[3]);
    p.z = pack2(src[4], src[5]); p.w = pack2(src[6], src[7]);
    *(u32x4*)(wih_f + (size_t)frag * 512u + l * 8u) = p;
  } else if (tid < 262144u) {
    unsigned int t2 = tid - 131072u;
    unsigned int frag = t2 >> 6, l = t2 & 63u;
    unsigned int cb = frag >> 4, ks = frag & 15u;
    unsigned int g  = cb * 16u + (l & 15u);
    unsigned int k0 = ks * 32u + ((l >> 4) << 3);
    const float* src = Whh + (size_t)g * 512u + k0;
    u32x4 p;
    p.x = pack2(src[0], src[1]); p.y = pack2(src[2], src[3]);
    p.z = pack2(src[4], src[5]); p.w = pack2(src[6], src[7]);
    *(u32x4*)(whh_f + (size_t)frag * 512u + l * 8u) = p;
  } else if (tid < 327680u) {
    // h0 frags: frag=(mb<64, ks<16); b=mb*16+(l&15); hcol0=ks*32+(l>>4)*8
    unsigned int t2 = tid - 262144u;
    unsigned int frag = t2 >> 6, l = t2 & 63u;
    unsigned int mb = frag >> 4, ks = frag & 15u;
    unsigned int b  = mb * 16u + (l & 15u);
    unsigned int c0 = ks * 32u + ((l >> 4) << 3);
    const float* src = rnn + (size_t)b * 1024u + c0;
    u32x4 p;
    p.x = pack2(src[0], src[1]); p.y = pack2(src[2], src[3]);
    p.z = pack2(src[4], src[5]); p.w = pack2(src[6], src[7]);
    *(u32x4*)(hf + (size_t)frag * 512u + l * 8u) = p;
  } else if (tid < 329728u) {
    unsigned int g = tid - 327680u;
    bias[g] = bih[g] + bhh[g];
  } else if (tid == 329728u) {
    __hip_atomic_store((unsigned int*)(ws + F_CTR), 0u,
                       __ATOMIC_RELAXED, __HIP_MEMORY_SCOPE_AGENT);
  } else if (tid >= 331776u && tid < 4526080u) {
    // x frags: frag=(t<64, mb<64, ks<16); b=mb*16+(l&15); k0=ks*32+(l>>4)*8
    unsigned int t2 = tid - 331776u;
    unsigned int frag = t2 >> 6, l = t2 & 63u;
    unsigned int ks = frag & 15u, mb = (frag >> 4) & 63u, t = frag >> 10;
    unsigned int b  = mb * 16u + (l & 15u);
    unsigned int k0 = ks * 32u + ((l >> 4) << 3);
    const float* src = xg + ((size_t)(b * 64u + t)) * 512u + k0;
    u32x4 p;
    p.x = pack2(src[0], src[1]); p.y = pack2(src[2], src[3]);
    p.z = pack2(src[4], src[5]); p.w = pack2(src[6], src[7]);
    *(u32x4*)(xbf + (size_t)frag * 512u + l * 8u) = p;
  }
}

// Big GEMM: x_proj[t] = x_t @ W_ih^T + bias, bf16 D-frag output.
// grid 8192 = t(64) x mtile(8) x ntile(16); tile 128M x 128N, K=512, BK=64.
__global__ void __launch_bounds__(256) gemm_xproj(unsigned char* __restrict__ ws) {
  const unsigned short* xbf = (const unsigned short*)(ws + F_XBF);
  const unsigned short* wih = (const unsigned short*)(ws + F_WIH);
  const float* bias = (const float*)(ws + F_BIAS);
  unsigned short* xproj = (unsigned short*)(ws + F_XPROJ);

  __shared__ __align__(16) unsigned char smem[65536];
  const int tid = threadIdx.x;
  const int w = tid >> 6, l = tid & 63;
  const int mh = w & 1, nh = w >> 1;
  const int bid = blockIdx.x;
  const int t = bid >> 7, mtile = (bid >> 4) & 7, ntile = bid & 15;

  f32x4 acc[4][4];
  {
    f32x4 z = {0.f, 0.f, 0.f, 0.f};
    #pragma unroll
    for (int i = 0; i < 4; ++i)
      #pragma unroll
      for (int j = 0; j < 4; ++j) acc[i][j] = z;
  }

  auto stage = [&](int kc, int buf) {
    unsigned char* ab = smem + buf * 16384;
    unsigned char* bb = smem + 32768 + buf * 16384;
    #pragma unroll
    for (int j = 0; j < 4; ++j) {
      int idx = w * 4 + j;
      int mb_l = idx >> 1, ksl = idx & 1;
      size_t frag = (size_t)(t * 64 + mtile * 8 + mb_l) * 16u + kc * 2 + ksl;
      gl_lds16(xbf + (frag * 64u + l) * 8u, ab + idx * 1024);
    }
    #pragma unroll
    for (int j = 0; j < 4; ++j) {
      int idx = w * 4 + j;
      int cb_l = idx >> 1, ksl = idx & 1;
      size_t frag = (size_t)(ntile * 8 + cb_l) * 16u + kc * 2 + ksl;
      gl_lds16(wih + (frag * 64u + l) * 8u, bb + idx * 1024);
    }
  };

  stage(0, 0);
  __syncthreads();
  for (int kc = 0; kc < 8; ++kc) {
    int cur = kc & 1;
    if (kc < 7) stage(kc + 1, cur ^ 1);
    unsigned char* ab = smem + cur * 16384;
    unsigned char* bb = smem + 32768 + cur * 16384;
    s16x8 afr[4][2], bfr[4][2];
    #pragma unroll
    for (int m = 0; m < 4; ++m)
      #pragma unroll
      for (int ksl = 0; ksl < 2; ++ksl)
        afr[m][ksl] = *(const s16x8*)(ab + ((mh * 4 + m) * 2 + ksl) * 1024 + l * 16);
    #pragma unroll
    for (int n = 0; n < 4; ++n)
      #pragma unroll
      for (int ksl = 0; ksl < 2; ++ksl)
        bfr[n][ksl] = *(const s16x8*)(bb + ((nh * 4 + n) * 2 + ksl) * 1024 + l * 16);
    #pragma unroll
    for (int m = 0; m < 4; ++m)
      #pragma unroll
      for (int n = 0; n < 4; ++n)
        #pragma unroll
        for (int ksl = 0; ksl < 2; ++ksl)
          acc[m][n] = __builtin_amdgcn_mfma_f32_16x16x32_bf16(
              afr[m][ksl], bfr[n][ksl], acc[m][n], 0, 0, 0);
    __syncthreads();
  }

  #pragma unroll
  for (int m = 0; m < 4; ++m) {
    int mb_abs = mtile * 8 + mh * 4 + m;
    #pragma unroll
    for (int n = 0; n < 4; ++n) {
      int n_abs = ntile * 8 + nh * 4 + n;
      float bc = bias[n_abs * 16 + (l & 15)];
      u16x4 p;
      #pragma unroll
      for (int r = 0; r < 4; ++r) p[r] = f2bf(acc[m][n][r] + bc);
      *(u16x4*)(xproj + ((size_t)(t * 64 + mb_abs) * 128u + n_abs) * 256u + l * 4u) = p;
    }
  }
}

// Persistent spin-barrier recurrence: 256 blocks x 256 threads, 1 block/CU.
// Block (mt,ht): 64 rows x 32 h-cols. Wave w = mb index (16 rows, all 32 cols).
// LDS: [0,128K) W frags, [128K,144K) dones [64][64], [144K,153K) Hl [64][36].
__global__ void __launch_bounds__(256, 1) persist_lock(
    const float* __restrict__ rnn, const float* __restrict__ dones,
    unsigned char* __restrict__ ws, float* __restrict__ out) {
  const unsigned short* whh = (const unsigned short*)(ws + F_WHH);
  const unsigned short* xproj = (const unsigned short*)(ws + F_XPROJ);
  unsigned int* ctr = (unsigned int*)(ws + F_CTR);
  unsigned short* hf0 = (unsigned short*)(ws + F_HF0);
  unsigned short* hf1 = (unsigned short*)(ws + F_HF1);

  __shared__ __align__(16) unsigned char smem[156672];
  float* dn_lds = (float*)(smem + 131072);
  float* Hl     = (float*)(smem + 147456);

  const int tid = threadIdx.x;
  const int w = tid >> 6, l = tid & 63;
  const int mt = (int)blockIdx.x >> 4, ht = (int)blockIdx.x & 15;

  // ---- prologue: W tile (128 frags) + dones -> LDS, c0 -> regs ----
  #pragma unroll
  for (int j = 0; j < 32; ++j) {
    int idx = w * 32 + j;
    int gcb = idx >> 4, ks = idx & 15;
    int cb = (gcb >> 1) * 32 + ht * 2 + (gcb & 1);
    gl_lds16(whh + ((size_t)(cb * 16 + ks) * 64u + l) * 8u, smem + idx * 1024);
  }
  #pragma unroll
  for (int j = 0; j < 4; ++j) {
    int chunk = w * 4 + j;
    gl_lds16(dones + (size_t)mt * 4096u + chunk * 256u + l * 4u,
             smem + 131072 + chunk * 1024);
  }
  f32x4 cold[2];
  #pragma unroll
  for (int cbl = 0; cbl < 2; ++cbl)
    #pragma unroll
    for (int r = 0; r < 4; ++r) {
      int b = (mt * 4 + w) * 16 + ((l >> 4) << 2) + r;
      int hcol = ht * 32 + cbl * 16 + (l & 15);
      cold[cbl][r] = rnn[(size_t)b * 1024u + 512u + hcol];
    }
  __syncthreads();

  #pragma unroll 1
  for (int t = 0; t < 64; ++t) {
    const unsigned short* hsrc = (t & 1) ? hf1 : hf0;
    unsigned short* hdst = (t & 1) ? hf0 : hf1;

    // A operand: wave's mb frags, agent-scope coherent loads
    s16x8 areg[16];
    #pragma unroll
    for (int ks = 0; ks < 16; ++ks)
      areg[ks] = aload16(hsrc + ((size_t)((mt * 4 + w) * 16 + ks) * 64u + l) * 8u);

    // acc init = xproj (bias folded in)
    f32x4 acc[4][2];
    #pragma unroll
    for (int g = 0; g < 4; ++g)
      #pragma unroll
      for (int cbl = 0; cbl < 2; ++cbl) {
        int n_abs = g * 32 + ht * 2 + cbl;
        u16x4 xv = __builtin_nontemporal_load((const u16x4*)(xproj +
            ((size_t)(t * 64 + mt * 4 + w) * 128u + n_abs) * 256u + l * 4u));
        #pragma unroll
        for (int r = 0; r < 4; ++r) acc[g][cbl][r] = bf2f(xv[r]);
      }

    // MFMA: 16 ks x 8 (g,cbl), B frags from resident LDS W tile
    #pragma unroll
    for (int ks = 0; ks < 16; ++ks) {
      s16x8 bfr[4][2];
      #pragma unroll
      for (int g = 0; g < 4; ++g)
        #pragma unroll
        for (int cbl = 0; cbl < 2; ++cbl)
          bfr[g][cbl] = *(const s16x8*)(smem + ((g * 2 + cbl) * 16 + ks) * 1024 + l * 16);
      #pragma unroll
      for (int g = 0; g < 4; ++g)
        #pragma unroll
        for (int cbl = 0; cbl < 2; ++cbl)
          acc[g][cbl] = __builtin_amdgcn_mfma_f32_16x16x32_bf16(
              areg[ks], bfr[g][cbl], acc[g][cbl], 0, 0, 0);
    }

    // ---- LSTM cell + outputs; masked h -> Hl, masked c -> regs ----
    #pragma unroll
    for (int cbl = 0; cbl < 2; ++cbl)
      #pragma unroll
      for (int r = 0; r < 4; ++r) {
        float gi = sigm(acc[0][cbl][r]);
        float gf = sigm(acc[1][cbl][r]);
        float gg = tanhf(acc[2][cbl][r]);
        float go = sigm(acc[3][cbl][r]);
        int lrow = w * 16 + ((l >> 4) << 2) + r;
        float cc = gf * cold[cbl][r] + gi * gg;
        float h = go * tanhf(cc);
        float keep = 1.0f - dn_lds[lrow * 64 + t];   // next step's mask fold-in
        cold[cbl][r] = cc * keep;
        Hl[lrow * 36 + cbl * 16 + (l & 15)] = h * keep;
        int b = mt * 64 + lrow;
        int hcol = ht * 32 + cbl * 16 + (l & 15);
        out[((size_t)(b * 64 + t)) * 512u + hcol] = h;
        out[OUT_HS + ((size_t)(t * 1024 + b)) * 512u + hcol] = h;
        out[OUT_CS + ((size_t)(t * 1024 + b)) * 512u + hcol] = cc;
        if (t == 63) {
          out[OUT_RNN + (size_t)b * 1024u + hcol] = h;
          out[OUT_RNN + (size_t)b * 1024u + 512u + hcol] = cc;
        }
      }
    __syncthreads();   // Hl complete

    // repack masked h -> hdst frags (mb = mt*4 + tid>>6, ks = ht), agent store
    {
      const int mbl = tid >> 6, lp = tid & 63;
      const float* hr = Hl + (size_t)(mbl * 16 + (lp & 15)) * 36u + ((lp >> 4) << 3);
      u32x4 p;
      p.x = pack2(hr[0], hr[1]); p.y = pack2(hr[2], hr[3]);
      p.z = pack2(hr[4], hr[5]); p.w = pack2(hr[6], hr[7]);
      astore16(hdst + ((size_t)((mt * 4 + mbl) * 16 + ht) * 64u + lp) * 8u, p);
    }

    // ---- global spin barrier (skip after final step) ----
    if (t < 63) {
      __syncthreads();
      if (tid == 0) {
        __hip_atomic_fetch_add(ctr, 1u, __ATOMIC_RELEASE, __HIP_MEMORY_SCOPE_AGENT);
        unsigned int target = 256u * (unsigned int)(t + 1);
        while (__hip_atomic_load(ctr, __ATOMIC_ACQUIRE, __HIP_MEMORY_SCOPE_AGENT) < target)
          __builtin_amdgcn_s_sleep(8);
      }
      __syncthreads();
    }
  }
}

// ====================== FALLBACK (round-1, verified) ======================

__global__ void __launch_bounds__(256) prep_kernel(
    const float* __restrict__ rnn, const float* __restrict__ Wih,
    const float* __restrict__ Whh, const float* __restrict__ bih,
    const float* __restrict__ bhh, unsigned char* __restrict__ ws) {
  unsigned int tid = blockIdx.x * 256u + threadIdx.x;
  unsigned short* wcf = (unsigned short*)(ws + WC_OFF);
  unsigned short* hf  = (unsigned short*)(ws + HF_OFF);
  float* cf   = (float*)(ws + CF_OFF);
  float* bias = (float*)(ws + BIAS_OFF);
  if (tid < 262144u) {
    unsigned int frag = tid >> 6, l = tid & 63u;
    unsigned int cb = frag >> 5, ks = frag & 31u;
    unsigned int g  = cb * 16u + (l & 15u);
    unsigned int k0 = ks * 32u + ((l >> 4) << 3);
    const float* src = (k0 < 512u) ? (Wih + g * 512u + k0) : (Whh + g * 512u + (k0 - 512u));
    u32x4 p;
    p.x = pack2(src[0], src[1]); p.y = pack2(src[2], src[3]);
    p.z = pack2(src[4], src[5]); p.w = pack2(src[6], src[7]);
    *(u32x4*)(wcf + (size_t)frag * 512u + l * 8u) = p;
  } else if (tid < 327680u) {
    unsigned int t2 = tid - 262144u;
    unsigned int frag = t2 >> 6, l = t2 & 63u;
    unsigned int mb = frag >> 4, ks = frag & 15u;
    unsigned int b  = mb * 16u + (l & 15u);
    unsigned int c0 = ks * 32u + ((l >> 4) << 3);
    const float* src = rnn + (size_t)b * 1024u + c0;
    u32x4 p;
    p.x = pack2(src[0], src[1]); p.y = pack2(src[2], src[3]);
    p.z = pack2(src[4], src[5]); p.w = pack2(src[6], src[7]);
    *(u32x4*)(hf + (size_t)frag * 512u + l * 8u) = p;
  } else if (tid < 458752u) {
    unsigned int t2 = tid - 327680u;
    unsigned int frag = t2 >> 6, l = t2 & 63u;
    unsigned int mb = frag >> 5, cfi = frag & 31u;
    unsigned int hcol = cfi * 16u + (l & 15u);
    f32x4 p;
    #pragma unroll
    for (int r = 0; r < 4; ++r) {
      unsigned int b = mb * 16u + ((l >> 4) << 2) + r;
      p[r] = rnn[(size_t)b * 1024u + 512u + hcol];
    }
    *(f32x4*)(cf + (size_t)frag * 256u + l * 4u) = p;
  } else if (tid < 460800u) {
    unsigned int g = tid - 458752u;
    bias[g] = bih[g] + bhh[g];
  }
}

__global__ void __launch_bounds__(256) step_kernel(
    const float* __restrict__ xg, const float* __restrict__ dones,
    unsigned char* __restrict__ ws, float* __restrict__ out, int t) {
  const unsigned short* wcf = (const unsigned short*)(ws + WC_OFF);
  unsigned short* hf = (unsigned short*)(ws + HF_OFF);
  float* cf = (float*)(ws + CF_OFF);
  const float* bias = (const float*)(ws + BIAS_OFF);

  __shared__ __align__(16) unsigned char smem[49152];
  const int tid = threadIdx.x;
  const int w = tid >> 6, l = tid & 63;
  const int mh = w & 1, ch = w >> 1;
  const int mt = (int)blockIdx.x >> 4, ht = (int)blockIdx.x & 15;

  f32x4 acc[2][4];
  {
    f32x4 z = {0.f, 0.f, 0.f, 0.f};
    #pragma unroll
    for (int i = 0; i < 2; ++i)
      #pragma unroll
      for (int j = 0; j < 4; ++j) acc[i][j] = z;
  }

  f32x4 xv[2][2];

  auto stage_load = [&](int kc, int buf) {
    unsigned char* bb = smem + 16384 + buf * 16384;
    #pragma unroll
    for (int j = 0; j < 4; ++j) {
      int idx = w * 4 + j;
      int g = idx >> 2, cbl = (idx >> 1) & 1, ksl = idx & 1;
      int cb = g * 32 + ht * 2 + cbl;
      int ks = kc * 2 + ksl;
      const unsigned short* src = wcf + ((size_t)(cb * 32 + ks) * 64u + l) * 8u;
      gl_lds16(src, bb + idx * 1024);
    }
    unsigned char* ab = smem + buf * 8192;
    if (kc >= 8) {
      #pragma unroll
      for (int j = 0; j < 2; ++j) {
        int idx = w * 2 + j;
        int ksh = (kc - 8) * 2 + j;
        int mb_abs = mt * 4 + w;
        const unsigned short* src = hf + ((size_t)(mb_abs * 16 + ksh) * 64u + l) * 8u;
        gl_lds16(src, ab + idx * 1024);
      }
    } else {
      #pragma unroll
      for (int j = 0; j < 2; ++j) {
        int ks = kc * 2 + j;
        int b = mt * 64 + w * 16 + (l & 15);
        int k0 = ks * 32 + ((l >> 4) << 3);
        const float* src = xg + ((size_t)(b * 64 + t)) * 512u + k0;
        xv[j][0] = *(const f32x4*)src;
        xv[j][1] = *(const f32x4*)(src + 4);
      }
    }
  };
  auto stage_write = [&](int kc, int buf) {
    if (kc < 8) {
      unsigned char* ab = smem + buf * 8192;
      #pragma unroll
      for (int j = 0; j < 2; ++j) {
        int idx = w * 2 + j;
        u32x4 p;
        p.x = pack2(xv[j][0].x, xv[j][0].y); p.y = pack2(xv[j][0].z, xv[j][0].w);
        p.z = pack2(xv[j][1].x, xv[j][1].y); p.w = pack2(xv[j][1].z, xv[j][1].w);
        *(u32x4*)(ab + idx * 1024 + l * 16) = p;
      }
    }
  };

  stage_load(0, 0);
  stage_write(0, 0);
  __syncthreads();

  for (int kc = 0; kc < 16; ++kc) {
    int cur = kc & 1;
    if (kc < 15) stage_load(kc + 1, cur ^ 1);
    unsigned char* ab = smem + cur * 8192;
    unsigned char* bb = smem + 16384 + cur * 16384;
    s16x8 afr[2][2], bfr[4][2];
    #pragma unroll
    for (int mb2 = 0; mb2 < 2; ++mb2)
      #pragma unroll
      for (int ksl = 0; ksl < 2; ++ksl)
        afr[mb2][ksl] = *(const s16x8*)(ab + ((mh * 2 + mb2) * 2 + ksl) * 1024 + l * 16);
    #pragma unroll
    for (int g = 0; g < 4; ++g)
      #pragma unroll
      for (int ksl = 0; ksl < 2; ++ksl)
        bfr[g][ksl] = *(const s16x8*)(bb + (g * 4 + ch * 2 + ksl) * 1024 + l * 16);
    #pragma unroll
    for (int mb2 = 0; mb2 < 2; ++mb2)
      #pragma unroll
      for (int g = 0; g < 4; ++g)
        #pragma unroll
        for (int ksl = 0; ksl < 2; ++ksl)
          acc[mb2][g] = __builtin_amdgcn_mfma_f32_16x16x32_bf16(
              afr[mb2][ksl], bfr[g][ksl], acc[mb2][g], 0, 0, 0);
    if (kc < 15) stage_write(kc + 1, cur ^ 1);
    __syncthreads();
  }

  const int hcol = ht * 32 + ch * 16 + (l & 15);
  const float bi = bias[hcol], bf2 = bias[512 + hcol];
  const float bg = bias[1024 + hcol], bo = bias[1536 + hcol];
  float* Hl = (float*)smem;
  float* Cl = (float*)(smem + 9216);
  const int cfi = ht * 2 + ch;
  const int colL = ch * 16 + (l & 15);
  #pragma unroll
  for (int mb2 = 0; mb2 < 2; ++mb2) {
    const int mb_abs = mt * 4 + mh * 2 + mb2;
    const int fid = mb_abs * 32 + cfi;
    f32x4 cold = *(const f32x4*)(cf + (size_t)fid * 256u + l * 4u);
    f32x4 cmask;
    #pragma unroll
    for (int r = 0; r < 4; ++r) {
      float gi = sigm(acc[mb2][0][r] + bi);
      float gf = sigm(acc[mb2][1][r] + bf2);
      float gg = tanhf(acc[mb2][2][r] + bg);
      float go = sigm(acc[mb2][3][r] + bo);
      float c = gf * cold[r] + gi * gg;
      float h = go * tanhf(c);
      int brow = mb_abs * 16 + ((l >> 4) << 2) + r;
      float keep = 1.0f - dones[brow * 64 + t];
      cmask[r] = c * keep;
      int rowL = mh * 32 + mb2 * 16 + ((l >> 4) << 2) + r;
      Hl[rowL * 36 + colL] = h;
      Cl[rowL * 36 + colL] = c;
    }
    *(f32x4*)(cf + (size_t)fid * 256u + l * 4u) = cmask;
  }
  __syncthreads();

  {
    const int mb2f = tid >> 6, lp = tid & 63;
    const int mb_abs = mt * 4 + mb2f;
    const int rowL = mb2f * 16 + (lp & 15);
    const int c0 = (lp >> 4) << 3;
    const int brow = mt * 64 + rowL;
    const float keep = 1.0f - dones[brow * 64 + t];
    const float* hr = Hl + rowL * 36 + c0;
    u32x4 p;
    p.x = pack2(hr[0] * keep, hr[1] * keep);
    p.y = pack2(hr[2] * keep, hr[3] * keep);
    p.z = pack2(hr[4] * keep, hr[5] * keep);
    p.w = pack2(hr[6] * keep, hr[7] * keep);
    *(u32x4*)(hf + ((size_t)(mb_abs * 16 + ht) * 64u + lp) * 8u) = p;
  }
  {
    const int row = tid & 63, cg2 = tid >> 6;
    const int b = mt * 64 + row;
    const int c0 = cg2 * 8;
    const float* hr = Hl + row * 36 + c0;
    const float* cr = Cl + row * 36 + c0;
    f32x4 h0 = *(const f32x4*)hr,  h1 = *(const f32x4*)(hr + 4);
    f32x4 cc0 = *(const f32x4*)cr, cc1 = *(const f32x4*)(cr + 4);
    const int colg = ht * 32 + c0;
    size_t xoff = ((size_t)(b * 64 + t)) * 512u + colg;
    *(f32x4*)(out + xoff) = h0; *(f32x4*)(out + xoff + 4) = h1;
    size_t hoff = OUT_HS + ((size_t)(t * 1024 + b)) * 512u + colg;
    *(f32x4*)(out + hoff) = h0; *(f32x4*)(out + hoff + 4) = h1;
    size_t coff = OUT_CS + ((size_t)(t * 1024 + b)) * 512u + colg;
    *(f32x4*)(out + coff) = cc0; *(f32x4*)(out + coff + 4) = cc1;
    if (t == 63) {
      size_t roff = OUT_RNN + (size_t)b * 1024u + colg;
      *(f32x4*)(out + roff) = h0;        *(f32x4*)(out + roff + 4) = h1;
      *(f32x4*)(out + roff + 512) = cc0; *(f32x4*)(out + roff + 516) = cc1;
    }
  }
}

extern "C" void kernel_launch(void* const* d_in, const int* in_sizes, int n_in,
                              void* d_out, int out_size, void* d_ws, size_t ws_size,
                              hipStream_t stream) {
  const float* xg  = (const float*)d_in[0];
  const float* rnn = (const float*)d_in[1];
  const float* dn  = (const float*)d_in[2];
  const float* Wih = (const float*)d_in[3];
  const float* Whh = (const float*)d_in[4];
  const float* bih = (const float*)d_in[5];
  const float* bhh = (const float*)d_in[6];
  float* out = (float*)d_out;
  unsigned char* ws = (unsigned char*)d_ws;
  (void)in_sizes; (void)n_in; (void)out_size;

  if (ws_size >= (size_t)F_NEED) {
    prep_fast<<<17680, 256, 0, stream>>>(xg, rnn, Wih, Whh, bih, bhh, ws);
    gemm_xproj<<<8192, 256, 0, stream>>>(ws);
    persist_lock<<<256, 256, 0, stream>>>(rnn, dn, ws, out);
  } else {
    prep_kernel<<<1800, 256, 0, stream>>>(rnn, Wih, Whh, bih, bhh, ws);
    for (int t = 0; t < 64; ++t)
      step_kernel<<<256, 256, 0, stream>>>(xg, dn, ws, out, t);
  }
}

// Round 9
// 1354.291 us; speedup vs baseline: 5.0655x; 1.6420x over previous
//
#include <hip/hip_runtime.h>
#include <stdint.h>

// PolicyCoreRNN: LSTM, B=1024, T=64, H=I=512.
// Round 9: round-8 spin-barrier skeleton (VERIFIED) with bandwidth fixes:
// 512 thr/block (8 waves, 2/SIMD), f32x4 nontemporal epilogue stores via
// LDS staging (full 128B lines), per-mt barriers (16 counters, 16 blocks
// each, XCD-grouped via mt=blockIdx&15), dones as bf16 in LDS.

// ---------- round-1 (fallback) ws layout ----------
#define WC_OFF   0u
#define HF_OFF   4194304u
#define CF_OFF   5242880u
#define BIAS_OFF 7340032u
// ---------- fast-path ws layout (bytes) ----------
#define F_WIH   0u           // 2 MiB  bf16 W_ih frags (cb*16+ks)*1024
#define F_WHH   2097152u     // 2 MiB  bf16 W_hh frags
#define F_HF0   4194304u     // 1 MiB  bf16 h-state frags buf0 (mb*16+ks)*1024
#define F_HF1   5242880u     // 1 MiB  bf16 h-state frags buf1
#define F_BIAS  6291456u     // 8 KiB  f32 b_ih+b_hh
#define F_CTR   6299648u     // 16 barrier counters, 128B apart
#define F_XBF   7340032u     // 64 MiB bf16 x frags ((t*64+mb)*16+ks)*1024
#define F_XPROJ 74448896u    // 256 MiB bf16 x_proj D-frags ((t*64+mb)*128+n)*512
#define F_NEED  342884352u
// out (f32 elements): x | new_rnn_states | h_stack | c_stack
#define OUT_RNN  33554432u
#define OUT_HS   34603008u
#define OUT_CS   68157440u

typedef __attribute__((ext_vector_type(4))) float f32x4;
typedef __attribute__((ext_vector_type(8))) short s16x8;
typedef __attribute__((ext_vector_type(4))) unsigned int u32x4;
typedef __attribute__((ext_vector_type(4))) unsigned short u16x4;

__device__ __forceinline__ unsigned short f2bf(float f) {
  union { float f; unsigned int u; } v; v.f = f;
  return (unsigned short)((v.u + 0x7FFFu + ((v.u >> 16) & 1u)) >> 16);
}
__device__ __forceinline__ float bf2f(unsigned short s) {
  union { unsigned int u; float f; } v; v.u = ((unsigned int)s) << 16;
  return v.f;
}
__device__ __forceinline__ unsigned int pack2(float a, float b) {
  return (unsigned int)f2bf(a) | ((unsigned int)f2bf(b) << 16);
}
__device__ __forceinline__ float sigm(float x) { return 1.0f / (1.0f + __expf(-x)); }

__device__ __forceinline__ void gl_lds16(const void* g, void* lds) {
  __builtin_amdgcn_global_load_lds(
      (const __attribute__((address_space(1))) unsigned int*)g,
      (__attribute__((address_space(3))) unsigned int*)lds, 16, 0, 0);
}

// agent-scope (device-coherent) 16B load/store as 2x u64 atomics
__device__ __forceinline__ s16x8 aload16(const unsigned short* p) {
  union { unsigned long long q[2]; s16x8 v; } u;
  u.q[0] = __hip_atomic_load((const unsigned long long*)p,
                             __ATOMIC_RELAXED, __HIP_MEMORY_SCOPE_AGENT);
  u.q[1] = __hip_atomic_load((const unsigned long long*)(p + 4),
                             __ATOMIC_RELAXED, __HIP_MEMORY_SCOPE_AGENT);
  return u.v;
}
__device__ __forceinline__ void astore16(unsigned short* p, u32x4 v) {
  union { u32x4 v; unsigned long long q[2]; } u; u.v = v;
  __hip_atomic_store((unsigned long long*)p, u.q[0],
                     __ATOMIC_RELAXED, __HIP_MEMORY_SCOPE_AGENT);
  __hip_atomic_store((unsigned long long*)(p + 4), u.q[1],
                     __ATOMIC_RELAXED, __HIP_MEMORY_SCOPE_AGENT);
}

// Fragment conventions (16x16x32 bf16 MFMA):
//  A/B input frag (1KB): lane l holds index (l&15) of the 16-dim, k = ks*32+(l>>4)*8+e.
//  D frag: col = l&15 (B dim), row = (l>>4)*4 + reg (A dim).  [m89-verified]

// ====================== FAST PATH ======================

__global__ void __launch_bounds__(256) prep_fast(
    const float* __restrict__ xg, const float* __restrict__ rnn,
    const float* __restrict__ Wih, const float* __restrict__ Whh,
    const float* __restrict__ bih, const float* __restrict__ bhh,
    unsigned char* __restrict__ ws) {
  unsigned int tid = blockIdx.x * 256u + threadIdx.x;
  unsigned short* wih_f = (unsigned short*)(ws + F_WIH);
  unsigned short* whh_f = (unsigned short*)(ws + F_WHH);
  unsigned short* hf    = (unsigned short*)(ws + F_HF0);
  float* bias = (float*)(ws + F_BIAS);
  unsigned short* xbf = (unsigned short*)(ws + F_XBF);
  if (tid < 131072u) {
    unsigned int frag = tid >> 6, l = tid & 63u;
    unsigned int cb = frag >> 4, ks = frag & 15u;
    unsigned int g  = cb * 16u + (l & 15u);
    unsigned int k0 = ks * 32u + ((l >> 4) << 3);
    const float* src = Wih + (size_t)g * 512u + k0;
    u32x4 p;
    p.x = pack2(src[0], src[1]); p.y = pack2(src[2], src[3]);
    p.z = pack2(src[4], src[5]); p.w = pack2(src[6], src[7]);
    *(u32x4*)(wih_f + (size_t)frag * 512u + l * 8u) = p;
  } else if (tid < 262144u) {
    unsigned int t2 = tid - 131072u;
    unsigned int frag = t2 >> 6, l = t2 & 63u;
    unsigned int cb = frag >> 4, ks = frag & 15u;
    unsigned int g  = cb * 16u + (l & 15u);
    unsigned int k0 = ks * 32u + ((l >> 4) << 3);
    const float* src = Whh + (size_t)g * 512u + k0;
    u32x4 p;
    p.x = pack2(src[0], src[1]); p.y = pack2(src[2], src[3]);
    p.z = pack2(src[4], src[5]); p.w = pack2(src[6], src[7]);
    *(u32x4*)(whh_f + (size_t)frag * 512u + l * 8u) = p;
  } else if (tid < 327680u) {
    unsigned int t2 = tid - 262144u;
    unsigned int frag = t2 >> 6, l = t2 & 63u;
    unsigned int mb = frag >> 4, ks = frag & 15u;
    unsigned int b  = mb * 16u + (l & 15u);
    unsigned int c0 = ks * 32u + ((l >> 4) << 3);
    const float* src = rnn + (size_t)b * 1024u + c0;
    u32x4 p;
    p.x = pack2(src[0], src[1]); p.y = pack2(src[2], src[3]);
    p.z = pack2(src[4], src[5]); p.w = pack2(src[6], src[7]);
    *(u32x4*)(hf + (size_t)frag * 512u + l * 8u) = p;
  } else if (tid < 329728u) {
    unsigned int g = tid - 327680u;
    bias[g] = bih[g] + bhh[g];
  } else if (tid < 329744u) {
    __hip_atomic_store((unsigned int*)(ws + F_CTR) + (tid - 329728u) * 32u, 0u,
                       __ATOMIC_RELAXED, __HIP_MEMORY_SCOPE_AGENT);
  } else if (tid >= 331776u && tid < 4526080u) {
    unsigned int t2 = tid - 331776u;
    unsigned int frag = t2 >> 6, l = t2 & 63u;
    unsigned int ks = frag & 15u, mb = (frag >> 4) & 63u, t = frag >> 10;
    unsigned int b  = mb * 16u + (l & 15u);
    unsigned int k0 = ks * 32u + ((l >> 4) << 3);
    const float* src = xg + ((size_t)(b * 64u + t)) * 512u + k0;
    u32x4 p;
    p.x = pack2(src[0], src[1]); p.y = pack2(src[2], src[3]);
    p.z = pack2(src[4], src[5]); p.w = pack2(src[6], src[7]);
    *(u32x4*)(xbf + (size_t)frag * 512u + l * 8u) = p;
  }
}

// Big GEMM: x_proj[t] = x_t @ W_ih^T + bias, bf16 D-frag output.
// grid 8192 = t(64) x mtile(8) x ntile(16); tile 128M x 128N, K=512, BK=64.
__global__ void __launch_bounds__(256) gemm_xproj(unsigned char* __restrict__ ws) {
  const unsigned short* xbf = (const unsigned short*)(ws + F_XBF);
  const unsigned short* wih = (const unsigned short*)(ws + F_WIH);
  const float* bias = (const float*)(ws + F_BIAS);
  unsigned short* xproj = (unsigned short*)(ws + F_XPROJ);

  __shared__ __align__(16) unsigned char smem[65536];
  const int tid = threadIdx.x;
  const int w = tid >> 6, l = tid & 63;
  const int mh = w & 1, nh = w >> 1;
  const int bid = blockIdx.x;
  const int t = bid >> 7, mtile = (bid >> 4) & 7, ntile = bid & 15;

  f32x4 acc[4][4];
  {
    f32x4 z = {0.f, 0.f, 0.f, 0.f};
    #pragma unroll
    for (int i = 0; i < 4; ++i)
      #pragma unroll
      for (int j = 0; j < 4; ++j) acc[i][j] = z;
  }

  auto stage = [&](int kc, int buf) {
    unsigned char* ab = smem + buf * 16384;
    unsigned char* bb = smem + 32768 + buf * 16384;
    #pragma unroll
    for (int j = 0; j < 4; ++j) {
      int idx = w * 4 + j;
      int mb_l = idx >> 1, ksl = idx & 1;
      size_t frag = (size_t)(t * 64 + mtile * 8 + mb_l) * 16u + kc * 2 + ksl;
      gl_lds16(xbf + (frag * 64u + l) * 8u, ab + idx * 1024);
    }
    #pragma unroll
    for (int j = 0; j < 4; ++j) {
      int idx = w * 4 + j;
      int cb_l = idx >> 1, ksl = idx & 1;
      size_t frag = (size_t)(ntile * 8 + cb_l) * 16u + kc * 2 + ksl;
      gl_lds16(wih + (frag * 64u + l) * 8u, bb + idx * 1024);
    }
  };

  stage(0, 0);
  __syncthreads();
  for (int kc = 0; kc < 8; ++kc) {
    int cur = kc & 1;
    if (kc < 7) stage(kc + 1, cur ^ 1);
    unsigned char* ab = smem + cur * 16384;
    unsigned char* bb = smem + 32768 + cur * 16384;
    s16x8 afr[4][2], bfr[4][2];
    #pragma unroll
    for (int m = 0; m < 4; ++m)
      #pragma unroll
      for (int ksl = 0; ksl < 2; ++ksl)
        afr[m][ksl] = *(const s16x8*)(ab + ((mh * 4 + m) * 2 + ksl) * 1024 + l * 16);
    #pragma unroll
    for (int n = 0; n < 4; ++n)
      #pragma unroll
      for (int ksl = 0; ksl < 2; ++ksl)
        bfr[n][ksl] = *(const s16x8*)(bb + ((nh * 4 + n) * 2 + ksl) * 1024 + l * 16);
    #pragma unroll
    for (int m = 0; m < 4; ++m)
      #pragma unroll
      for (int n = 0; n < 4; ++n)
        #pragma unroll
        for (int ksl = 0; ksl < 2; ++ksl)
          acc[m][n] = __builtin_amdgcn_mfma_f32_16x16x32_bf16(
              afr[m][ksl], bfr[n][ksl], acc[m][n], 0, 0, 0);
    __syncthreads();
  }

  #pragma unroll
  for (int m = 0; m < 4; ++m) {
    int mb_abs = mtile * 8 + mh * 4 + m;
    #pragma unroll
    for (int n = 0; n < 4; ++n) {
      int n_abs = ntile * 8 + nh * 4 + n;
      float bc = bias[n_abs * 16 + (l & 15)];
      u16x4 p;
      #pragma unroll
      for (int r = 0; r < 4; ++r) p[r] = f2bf(acc[m][n][r] + bc);
      *(u16x4*)(xproj + ((size_t)(t * 64 + mb_abs) * 128u + n_abs) * 256u + l * 4u) = p;
    }
  }
}

// Persistent spin-barrier recurrence: 256 blocks x 512 threads, 1 block/CU.
// mt = blockIdx&15 (group XCD-resident), ht = blockIdx>>4.
// Block (mt,ht): 64 rows x 32 h-cols. Wave w: (mbw=w>>1, cbl=w&1) -> 16x16.
// LDS: [0,128K) W frags; Hl f32[64][40]; Cl f32[64][40]; dn16 bf16[64][72].
#define P_HL  131072
#define P_CL  141312
#define P_DN  151552
__global__ void __launch_bounds__(512, 2) persist_lock(
    const float* __restrict__ rnn, const float* __restrict__ dones,
    unsigned char* __restrict__ ws, float* __restrict__ out) {
  const unsigned short* whh = (const unsigned short*)(ws + F_WHH);
  const unsigned short* xproj = (const unsigned short*)(ws + F_XPROJ);
  unsigned int* ctrs = (unsigned int*)(ws + F_CTR);
  unsigned short* hf0 = (unsigned short*)(ws + F_HF0);
  unsigned short* hf1 = (unsigned short*)(ws + F_HF1);

  __shared__ __align__(16) unsigned char smem[160768];
  float* Hl = (float*)(smem + P_HL);
  float* Cl = (float*)(smem + P_CL);
  unsigned short* dn16 = (unsigned short*)(smem + P_DN);

  const int tid = threadIdx.x;
  const int w = tid >> 6, l = tid & 63;
  const int mbw = w >> 1, cbl = w & 1;
  const int mt = (int)blockIdx.x & 15, ht = (int)blockIdx.x >> 4;

  // ---- prologue: W tile (128 frags) -> LDS, dones -> bf16 LDS, c0 -> regs ----
  #pragma unroll
  for (int j = 0; j < 16; ++j) {
    int idx = w * 16 + j;
    int gcb = idx >> 4, ks = idx & 15;
    int cb = (gcb >> 1) * 32 + ht * 2 + (gcb & 1);
    gl_lds16(whh + ((size_t)(cb * 16 + ks) * 64u + l) * 8u, smem + idx * 1024);
  }
  {
    const float* dsrc = dones + (size_t)mt * 4096u + tid * 8;
    f32x4 d0 = *(const f32x4*)dsrc, d1 = *(const f32x4*)(dsrc + 4);
    int row = tid >> 3, t0 = (tid & 7) * 8;
    u32x4 p;
    p.x = pack2(d0.x, d0.y); p.y = pack2(d0.z, d0.w);
    p.z = pack2(d1.x, d1.y); p.w = pack2(d1.z, d1.w);
    *(u32x4*)(dn16 + row * 72 + t0) = p;
  }
  f32x4 cold;
  #pragma unroll
  for (int r = 0; r < 4; ++r) {
    int b = mt * 64 + mbw * 16 + ((l >> 4) << 2) + r;
    cold[r] = rnn[(size_t)b * 1024u + 512u + ht * 32 + cbl * 16 + (l & 15)];
  }
  __syncthreads();

  #pragma unroll 1
  for (int t = 0; t < 64; ++t) {
    const unsigned short* hsrc = (t & 1) ? hf1 : hf0;
    unsigned short* hdst = (t & 1) ? hf0 : hf1;

    // A operand: wave's mb frags, agent-scope coherent loads
    s16x8 areg[16];
    #pragma unroll
    for (int ks = 0; ks < 16; ++ks)
      areg[ks] = aload16(hsrc + ((size_t)((mt * 4 + mbw) * 16 + ks) * 64u + l) * 8u);

    // acc init = xproj (bias folded in)
    f32x4 acc[4];
    #pragma unroll
    for (int g = 0; g < 4; ++g) {
      int n_abs = g * 32 + ht * 2 + cbl;
      u16x4 xv = __builtin_nontemporal_load((const u16x4*)(xproj +
          ((size_t)(t * 64 + mt * 4 + mbw) * 128u + n_abs) * 256u + l * 4u));
      #pragma unroll
      for (int r = 0; r < 4; ++r) acc[g][r] = bf2f(xv[r]);
    }

    // MFMA: 16 ks x 4 gates, B frags from resident LDS W tile
    #pragma unroll
    for (int ks = 0; ks < 16; ++ks) {
      s16x8 bfr[4];
      #pragma unroll
      for (int g = 0; g < 4; ++g)
        bfr[g] = *(const s16x8*)(smem + ((g * 2 + cbl) * 16 + ks) * 1024 + l * 16);
      #pragma unroll
      for (int g = 0; g < 4; ++g)
        acc[g] = __builtin_amdgcn_mfma_f32_16x16x32_bf16(areg[ks], bfr[g], acc[g], 0, 0, 0);
    }

    // ---- LSTM cell: h,c (unmasked) -> LDS; masked c -> regs ----
    #pragma unroll
    for (int r = 0; r < 4; ++r) {
      float gi = sigm(acc[0][r]);
      float gf = sigm(acc[1][r]);
      float gg = tanhf(acc[2][r]);
      float go = sigm(acc[3][r]);
      int lrow = mbw * 16 + ((l >> 4) << 2) + r;
      float cc = gf * cold[r] + gi * gg;
      float h = go * tanhf(cc);
      float keep = 1.0f - bf2f(dn16[lrow * 72 + t]);   // next step's mask
      cold[r] = cc * keep;
      Hl[lrow * 40 + cbl * 16 + (l & 15)] = h;
      Cl[lrow * 40 + cbl * 16 + (l & 15)] = cc;
    }
    __syncthreads();   // Hl/Cl complete; all waves done with areg reads

    // ---- vectorized epilogue: f32x4 nontemporal stores (full lines) ----
    {
      int row = tid >> 3, ch = tid & 7;
      int b = mt * 64 + row;
      f32x4 hv = *(const f32x4*)(Hl + row * 40 + ch * 4);
      f32x4 cv = *(const f32x4*)(Cl + row * 40 + ch * 4);
      int colg = ht * 32 + ch * 4;
      __builtin_nontemporal_store(hv, (f32x4*)(out + ((size_t)(b * 64 + t)) * 512u + colg));
      __builtin_nontemporal_store(hv, (f32x4*)(out + OUT_HS + ((size_t)(t * 1024 + b)) * 512u + colg));
      __builtin_nontemporal_store(cv, (f32x4*)(out + OUT_CS + ((size_t)(t * 1024 + b)) * 512u + colg));
      if (t == 63) {
        __builtin_nontemporal_store(hv, (f32x4*)(out + OUT_RNN + (size_t)b * 1024u + colg));
        __builtin_nontemporal_store(cv, (f32x4*)(out + OUT_RNN + (size_t)b * 1024u + 512u + colg));
      }
    }

    if (t < 63) {
      // repack masked h -> hdst frags (mb = mt*4 + tid>>6, ks = ht)
      if (tid < 256) {
        const int mbl = tid >> 6, lp = tid & 63;
        const int row = mbl * 16 + (lp & 15);
        const float keep = 1.0f - bf2f(dn16[row * 72 + t]);
        const float* hr = Hl + (size_t)row * 40u + ((lp >> 4) << 3);
        u32x4 p;
        p.x = pack2(hr[0] * keep, hr[1] * keep);
        p.y = pack2(hr[2] * keep, hr[3] * keep);
        p.z = pack2(hr[4] * keep, hr[5] * keep);
        p.w = pack2(hr[6] * keep, hr[7] * keep);
        astore16(hdst + ((size_t)((mt * 4 + mbl) * 16 + ht) * 64u + lp) * 8u, p);
      }
      // ---- per-mt spin barrier (16 blocks/group) ----
      __syncthreads();
      if (tid == 0) {
        unsigned int* ctr = ctrs + mt * 32;
        __hip_atomic_fetch_add(ctr, 1u, __ATOMIC_RELEASE, __HIP_MEMORY_SCOPE_AGENT);
        unsigned int target = 16u * (unsigned int)(t + 1);
        while (__hip_atomic_load(ctr, __ATOMIC_ACQUIRE, __HIP_MEMORY_SCOPE_AGENT) < target)
          __builtin_amdgcn_s_sleep(2);
      }
      __syncthreads();
    }
  }
}

// ====================== FALLBACK (round-1, verified) ======================

__global__ void __launch_bounds__(256) prep_kernel(
    const float* __restrict__ rnn, const float* __restrict__ Wih,
    const float* __restrict__ Whh, const float* __restrict__ bih,
    const float* __restrict__ bhh, unsigned char* __restrict__ ws) {
  unsigned int tid = blockIdx.x * 256u + threadIdx.x;
  unsigned short* wcf = (unsigned short*)(ws + WC_OFF);
  unsigned short* hf  = (unsigned short*)(ws + HF_OFF);
  float* cf   = (float*)(ws + CF_OFF);
  float* bias = (float*)(ws + BIAS_OFF);
  if (tid < 262144u) {
    unsigned int frag = tid >> 6, l = tid & 63u;
    unsigned int cb = frag >> 5, ks = frag & 31u;
    unsigned int g  = cb * 16u + (l & 15u);
    unsigned int k0 = ks * 32u + ((l >> 4) << 3);
    const float* src = (k0 < 512u) ? (Wih + g * 512u + k0) : (Whh + g * 512u + (k0 - 512u));
    u32x4 p;
    p.x = pack2(src[0], src[1]); p.y = pack2(src[2], src[3]);
    p.z = pack2(src[4], src[5]); p.w = pack2(src[6], src[7]);
    *(u32x4*)(wcf + (size_t)frag * 512u + l * 8u) = p;
  } else if (tid < 327680u) {
    unsigned int t2 = tid - 262144u;
    unsigned int frag = t2 >> 6, l = t2 & 63u;
    unsigned int mb = frag >> 4, ks = frag & 15u;
    unsigned int b  = mb * 16u + (l & 15u);
    unsigned int c0 = ks * 32u + ((l >> 4) << 3);
    const float* src = rnn + (size_t)b * 1024u + c0;
    u32x4 p;
    p.x = pack2(src[0], src[1]); p.y = pack2(src[2], src[3]);
    p.z = pack2(src[4], src[5]); p.w = pack2(src[6], src[7]);
    *(u32x4*)(hf + (size_t)frag * 512u + l * 8u) = p;
  } else if (tid < 458752u) {
    unsigned int t2 = tid - 327680u;
    unsigned int frag = t2 >> 6, l = t2 & 63u;
    unsigned int mb = frag >> 5, cfi = frag & 31u;
    unsigned int hcol = cfi * 16u + (l & 15u);
    f32x4 p;
    #pragma unroll
    for (int r = 0; r < 4; ++r) {
      unsigned int b = mb * 16u + ((l >> 4) << 2) + r;
      p[r] = rnn[(size_t)b * 1024u + 512u + hcol];
    }
    *(f32x4*)(cf + (size_t)frag * 256u + l * 4u) = p;
  } else if (tid < 460800u) {
    unsigned int g = tid - 458752u;
    bias[g] = bih[g] + bhh[g];
  }
}

__global__ void __launch_bounds__(256) step_kernel(
    const float* __restrict__ xg, const float* __restrict__ dones,
    unsigned char* __restrict__ ws, float* __restrict__ out, int t) {
  const unsigned short* wcf = (const unsigned short*)(ws + WC_OFF);
  unsigned short* hf = (unsigned short*)(ws + HF_OFF);
  float* cf = (float*)(ws + CF_OFF);
  const float* bias = (const float*)(ws + BIAS_OFF);

  __shared__ __align__(16) unsigned char smem[49152];
  const int tid = threadIdx.x;
  const int w = tid >> 6, l = tid & 63;
  const int mh = w & 1, ch = w >> 1;
  const int mt = (int)blockIdx.x >> 4, ht = (int)blockIdx.x & 15;

  f32x4 acc[2][4];
  {
    f32x4 z = {0.f, 0.f, 0.f, 0.f};
    #pragma unroll
    for (int i = 0; i < 2; ++i)
      #pragma unroll
      for (int j = 0; j < 4; ++j) acc[i][j] = z;
  }

  f32x4 xv[2][2];

  auto stage_load = [&](int kc, int buf) {
    unsigned char* bb = smem + 16384 + buf * 16384;
    #pragma unroll
    for (int j = 0; j < 4; ++j) {
      int idx = w * 4 + j;
      int g = idx >> 2, cbl = (idx >> 1) & 1, ksl = idx & 1;
      int cb = g * 32 + ht * 2 + cbl;
      int ks = kc * 2 + ksl;
      const unsigned short* src = wcf + ((size_t)(cb * 32 + ks) * 64u + l) * 8u;
      gl_lds16(src, bb + idx * 1024);
    }
    unsigned char* ab = smem + buf * 8192;
    if (kc >= 8) {
      #pragma unroll
      for (int j = 0; j < 2; ++j) {
        int idx = w * 2 + j;
        int ksh = (kc - 8) * 2 + j;
        int mb_abs = mt * 4 + w;
        const unsigned short* src = hf + ((size_t)(mb_abs * 16 + ksh) * 64u + l) * 8u;
        gl_lds16(src, ab + idx * 1024);
      }
    } else {
      #pragma unroll
      for (int j = 0; j < 2; ++j) {
        int ks = kc * 2 + j;
        int b = mt * 64 + w * 16 + (l & 15);
        int k0 = ks * 32 + ((l >> 4) << 3);
        const float* src = xg + ((size_t)(b * 64 + t)) * 512u + k0;
        xv[j][0] = *(const f32x4*)src;
        xv[j][1] = *(const f32x4*)(src + 4);
      }
    }
  };
  auto stage_write = [&](int kc, int buf) {
    if (kc < 8) {
      unsigned char* ab = smem + buf * 8192;
      #pragma unroll
      for (int j = 0; j < 2; ++j) {
        int idx = w * 2 + j;
        u32x4 p;
        p.x = pack2(xv[j][0].x, xv[j][0].y); p.y = pack2(xv[j][0].z, xv[j][0].w);
        p.z = pack2(xv[j][1].x, xv[j][1].y); p.w = pack2(xv[j][1].z, xv[j][1].w);
        *(u32x4*)(ab + idx * 1024 + l * 16) = p;
      }
    }
  };

  stage_load(0, 0);
  stage_write(0, 0);
  __syncthreads();

  for (int kc = 0; kc < 16; ++kc) {
    int cur = kc & 1;
    if (kc < 15) stage_load(kc + 1, cur ^ 1);
    unsigned char* ab = smem + cur * 8192;
    unsigned char* bb = smem + 16384 + cur * 16384;
    s16x8 afr[2][2], bfr[4][2];
    #pragma unroll
    for (int mb2 = 0; mb2 < 2; ++mb2)
      #pragma unroll
      for (int ksl = 0; ksl < 2; ++ksl)
        afr[mb2][ksl] = *(const s16x8*)(ab + ((mh * 2 + mb2) * 2 + ksl) * 1024 + l * 16);
    #pragma unroll
    for (int g = 0; g < 4; ++g)
      #pragma unroll
      for (int ksl = 0; ksl < 2; ++ksl)
        bfr[g][ksl] = *(const s16x8*)(bb + (g * 4 + ch * 2 + ksl) * 1024 + l * 16);
    #pragma unroll
    for (int mb2 = 0; mb2 < 2; ++mb2)
      #pragma unroll
      for (int g = 0; g < 4; ++g)
        #pragma unroll
        for (int ksl = 0; ksl < 2; ++ksl)
          acc[mb2][g] = __builtin_amdgcn_mfma_f32_16x16x32_bf16(
              afr[mb2][ksl], bfr[g][ksl], acc[mb2][g], 0, 0, 0);
    if (kc < 15) stage_write(kc + 1, cur ^ 1);
    __syncthreads();
  }

  const int hcol = ht * 32 + ch * 16 + (l & 15);
  const float bi = bias[hcol], bf2 = bias[512 + hcol];
  const float bg = bias[1024 + hcol], bo = bias[1536 + hcol];
  float* Hl = (float*)smem;
  float* Cl = (float*)(smem + 9216);
  const int cfi = ht * 2 + ch;
  const int colL = ch * 16 + (l & 15);
  #pragma unroll
  for (int mb2 = 0; mb2 < 2; ++mb2) {
    const int mb_abs = mt * 4 + mh * 2 + mb2;
    const int fid = mb_abs * 32 + cfi;
    f32x4 cold = *(const f32x4*)(cf + (size_t)fid * 256u + l * 4u);
    f32x4 cmask;
    #pragma unroll
    for (int r = 0; r < 4; ++r) {
      float gi = sigm(acc[mb2][0][r] + bi);
      float gf = sigm(acc[mb2][1][r] + bf2);
      float gg = tanhf(acc[mb2][2][r] + bg);
      float go = sigm(acc[mb2][3][r] + bo);
      float c = gf * cold[r] + gi * gg;
      float h = go * tanhf(c);
      int brow = mb_abs * 16 + ((l >> 4) << 2) + r;
      float keep = 1.0f - dones[brow * 64 + t];
      cmask[r] = c * keep;
      int rowL = mh * 32 + mb2 * 16 + ((l >> 4) << 2) + r;
      Hl[rowL * 36 + colL] = h;
      Cl[rowL * 36 + colL] = c;
    }
    *(f32x4*)(cf + (size_t)fid * 256u + l * 4u) = cmask;
  }
  __syncthreads();

  {
    const int mb2f = tid >> 6, lp = tid & 63;
    const int mb_abs = mt * 4 + mb2f;
    const int rowL = mb2f * 16 + (lp & 15);
    const int c0 = (lp >> 4) << 3;
    const int brow = mt * 64 + rowL;
    const float keep = 1.0f - dones[brow * 64 + t];
    const float* hr = Hl + rowL * 36 + c0;
    u32x4 p;
    p.x = pack2(hr[0] * keep, hr[1] * keep);
    p.y = pack2(hr[2] * keep, hr[3] * keep);
    p.z = pack2(hr[4] * keep, hr[5] * keep);
    p.w = pack2(hr[6] * keep, hr[7] * keep);
    *(u32x4*)(hf + ((size_t)(mb_abs * 16 + ht) * 64u + lp) * 8u) = p;
  }
  {
    const int row = tid & 63, cg2 = tid >> 6;
    const int b = mt * 64 + row;
    const int c0 = cg2 * 8;
    const float* hr = Hl + row * 36 + c0;
    const float* cr = Cl + row * 36 + c0;
    f32x4 h0 = *(const f32x4*)hr,  h1 = *(const f32x4*)(hr + 4);
    f32x4 cc0 = *(const f32x4*)cr, cc1 = *(const f32x4*)(cr + 4);
    const int colg = ht * 32 + c0;
    size_t xoff = ((size_t)(b * 64 + t)) * 512u + colg;
    *(f32x4*)(out + xoff) = h0; *(f32x4*)(out + xoff + 4) = h1;
    size_t hoff = OUT_HS + ((size_t)(t * 1024 + b)) * 512u + colg;
    *(f32x4*)(out + hoff) = h0; *(f32x4*)(out + hoff + 4) = h1;
    size_t coff = OUT_CS + ((size_t)(t * 1024 + b)) * 512u + colg;
    *(f32x4*)(out + coff) = cc0; *(f32x4*)(out + coff + 4) = cc1;
    if (t == 63) {
      size_t roff = OUT_RNN + (size_t)b * 1024u + colg;
      *(f32x4*)(out + roff) = h0;        *(f32x4*)(out + roff + 4) = h1;
      *(f32x4*)(out + roff + 512) = cc0; *(f32x4*)(out + roff + 516) = cc1;
    }
  }
}

extern "C" void kernel_launch(void* const* d_in, const int* in_sizes, int n_in,
                              void* d_out, int out_size, void* d_ws, size_t ws_size,
                              hipStream_t stream) {
  const float* xg  = (const float*)d_in[0];
  const float* rnn = (const float*)d_in[1];
  const float* dn  = (const float*)d_in[2];
  const float* Wih = (const float*)d_in[3];
  const float* Whh = (const float*)d_in[4];
  const float* bih = (const float*)d_in[5];
  const float* bhh = (const float*)d_in[6];
  float* out = (float*)d_out;
  unsigned char* ws = (unsigned char*)d_ws;
  (void)in_sizes; (void)n_in; (void)out_size;

  if (ws_size >= (size_t)F_NEED) {
    prep_fast<<<17680, 256, 0, stream>>>(xg, rnn, Wih, Whh, bih, bhh, ws);
    gemm_xproj<<<8192, 256, 0, stream>>>(ws);
    persist_lock<<<256, 512, 0, stream>>>(rnn, dn, ws, out);
  } else {
    prep_kernel<<<1800, 256, 0, stream>>>(rnn, Wih, Whh, bih, bhh, ws);
    for (int t = 0; t < 64; ++t)
      step_kernel<<<256, 256, 0, stream>>>(xg, dn, ws, out, t);
  }
}

// Round 10
// 1232.425 us; speedup vs baseline: 5.5664x; 1.0989x over previous
//
#include <hip/hip_runtime.h>
#include <stdint.h>

// PolicyCoreRNN: LSTM, B=1024, T=64, H=I=512.
// Round 10: de-serialize round-9 (verified skeleton). (1) output stores move
// AFTER the spin-barrier release and the join barrier is a raw s_barrier with
// lgkmcnt-only wait -> stores drain under next step's compute instead of
// inside the release's vmcnt(0). (2) h-exchange frags in SPLIT-u64 layout
// (low-8B | high-8B arrays) -> both atomic accesses fully coalesced.
// (3) xproj folded post-MFMA so its HBM latency hides under the MFMA phase.

// ---------- round-1 (fallback) ws layout ----------
#define WC_OFF   0u
#define HF_OFF   4194304u
#define CF_OFF   5242880u
#define BIAS_OFF 7340032u
// ---------- fast-path ws layout (bytes) ----------
#define F_WIH   0u           // 2 MiB  bf16 W_ih frags (cb*16+ks)*1024
#define F_WHH   2097152u     // 2 MiB  bf16 W_hh frags
#define F_HF0   4194304u     // 1 MiB  h frags buf0, SPLIT u64 layout
#define F_HF1   5242880u     // 1 MiB  h frags buf1
#define F_BIAS  6291456u     // 8 KiB  f32 b_ih+b_hh
#define F_CTR   6299648u     // 16 barrier counters, 128B apart
#define F_XBF   7340032u     // 64 MiB bf16 x frags ((t*64+mb)*16+ks)*1024
#define F_XPROJ 74448896u    // 256 MiB bf16 x_proj D-frags ((t*64+mb)*128+n)*512
#define F_NEED  342884352u
// out (f32 elements): x | new_rnn_states | h_stack | c_stack
#define OUT_RNN  33554432u
#define OUT_HS   34603008u
#define OUT_CS   68157440u

typedef __attribute__((ext_vector_type(4))) float f32x4;
typedef __attribute__((ext_vector_type(8))) short s16x8;
typedef __attribute__((ext_vector_type(4))) unsigned int u32x4;
typedef __attribute__((ext_vector_type(4))) unsigned short u16x4;

__device__ __forceinline__ unsigned short f2bf(float f) {
  union { float f; unsigned int u; } v; v.f = f;
  return (unsigned short)((v.u + 0x7FFFu + ((v.u >> 16) & 1u)) >> 16);
}
__device__ __forceinline__ float bf2f(unsigned short s) {
  union { unsigned int u; float f; } v; v.u = ((unsigned int)s) << 16;
  return v.f;
}
__device__ __forceinline__ unsigned int pack2(float a, float b) {
  return (unsigned int)f2bf(a) | ((unsigned int)f2bf(b) << 16);
}
__device__ __forceinline__ float sigm(float x) { return 1.0f / (1.0f + __expf(-x)); }

__device__ __forceinline__ void gl_lds16(const void* g, void* lds) {
  __builtin_amdgcn_global_load_lds(
      (const __attribute__((address_space(1))) unsigned int*)g,
      (__attribute__((address_space(3))) unsigned int*)lds, 16, 0, 0);
}

// raw join barrier: drain LDS ops only (NOT vmcnt -> stores keep draining)
__device__ __forceinline__ void lds_barrier() {
  asm volatile("s_waitcnt lgkmcnt(0)" ::: "memory");
  __builtin_amdgcn_sched_barrier(0);
  __builtin_amdgcn_s_barrier();
}

// Fragment conventions (16x16x32 bf16 MFMA):
//  A/B input frag (1KB): lane l holds index (l&15) of the 16-dim, k = ks*32+(l>>4)*8+e.
//  D frag: col = l&15 (B dim), row = (l>>4)*4 + reg (A dim).  [m89-verified]
// h-exchange frag SPLIT layout (per frag f, 128 u64): hq[f*128 + l] = lane l
// elems e0..3 (low u64); hq[f*128 + 64 + l] = elems e4..7 (high u64).

// ====================== FAST PATH ======================

__global__ void __launch_bounds__(256) prep_fast(
    const float* __restrict__ xg, const float* __restrict__ rnn,
    const float* __restrict__ Wih, const float* __restrict__ Whh,
    const float* __restrict__ bih, const float* __restrict__ bhh,
    unsigned char* __restrict__ ws) {
  unsigned int tid = blockIdx.x * 256u + threadIdx.x;
  unsigned short* wih_f = (unsigned short*)(ws + F_WIH);
  unsigned short* whh_f = (unsigned short*)(ws + F_WHH);
  float* bias = (float*)(ws + F_BIAS);
  unsigned short* xbf = (unsigned short*)(ws + F_XBF);
  if (tid < 131072u) {
    unsigned int frag = tid >> 6, l = tid & 63u;
    unsigned int cb = frag >> 4, ks = frag & 15u;
    unsigned int g  = cb * 16u + (l & 15u);
    unsigned int k0 = ks * 32u + ((l >> 4) << 3);
    const float* src = Wih + (size_t)g * 512u + k0;
    u32x4 p;
    p.x = pack2(src[0], src[1]); p.y = pack2(src[2], src[3]);
    p.z = pack2(src[4], src[5]); p.w = pack2(src[6], src[7]);
    *(u32x4*)(wih_f + (size_t)frag * 512u + l * 8u) = p;
  } else if (tid < 262144u) {
    unsigned int t2 = tid - 131072u;
    unsigned int frag = t2 >> 6, l = t2 & 63u;
    unsigned int cb = frag >> 4, ks = frag & 15u;
    unsigned int g  = cb * 16u + (l & 15u);
    unsigned int k0 = ks * 32u + ((l >> 4) << 3);
    const float* src = Whh + (size_t)g * 512u + k0;
    u32x4 p;
    p.x = pack2(src[0], src[1]); p.y = pack2(src[2], src[3]);
    p.z = pack2(src[4], src[5]); p.w = pack2(src[6], src[7]);
    *(u32x4*)(whh_f + (size_t)frag * 512u + l * 8u) = p;
  } else if (tid < 327680u) {
    // h0 frags, SPLIT layout: frag=(mb<64, ks<16); b=mb*16+(l&15); c0=ks*32+(l>>4)*8
    unsigned int t2 = tid - 262144u;
    unsigned int frag = t2 >> 6, l = t2 & 63u;
    unsigned int mb = frag >> 4, ks = frag & 15u;
    unsigned int b  = mb * 16u + (l & 15u);
    unsigned int c0 = ks * 32u + ((l >> 4) << 3);
    const float* src = rnn + (size_t)b * 1024u + c0;
    union { u32x4 v; unsigned long long q[2]; } u;
    u.v.x = pack2(src[0], src[1]); u.v.y = pack2(src[2], src[3]);
    u.v.z = pack2(src[4], src[5]); u.v.w = pack2(src[6], src[7]);
    unsigned long long* hq = (unsigned long long*)(ws + F_HF0);
    hq[(size_t)frag * 128u + l] = u.q[0];
    hq[(size_t)frag * 128u + 64u + l] = u.q[1];
  } else if (tid < 329728u) {
    unsigned int g = tid - 327680u;
    bias[g] = bih[g] + bhh[g];
  } else if (tid < 329744u) {
    __hip_atomic_store((unsigned int*)(ws + F_CTR) + (tid - 329728u) * 32u, 0u,
                       __ATOMIC_RELAXED, __HIP_MEMORY_SCOPE_AGENT);
  } else if (tid >= 331776u && tid < 4526080u) {
    unsigned int t2 = tid - 331776u;
    unsigned int frag = t2 >> 6, l = t2 & 63u;
    unsigned int ks = frag & 15u, mb = (frag >> 4) & 63u, t = frag >> 10;
    unsigned int b  = mb * 16u + (l & 15u);
    unsigned int k0 = ks * 32u + ((l >> 4) << 3);
    const float* src = xg + ((size_t)(b * 64u + t)) * 512u + k0;
    u32x4 p;
    p.x = pack2(src[0], src[1]); p.y = pack2(src[2], src[3]);
    p.z = pack2(src[4], src[5]); p.w = pack2(src[6], src[7]);
    *(u32x4*)(xbf + (size_t)frag * 512u + l * 8u) = p;
  }
}

// Big GEMM: x_proj[t] = x_t @ W_ih^T + bias, bf16 D-frag output.
// grid 8192 = t(64) x mtile(8) x ntile(16); tile 128M x 128N, K=512, BK=64.
__global__ void __launch_bounds__(256) gemm_xproj(unsigned char* __restrict__ ws) {
  const unsigned short* xbf = (const unsigned short*)(ws + F_XBF);
  const unsigned short* wih = (const unsigned short*)(ws + F_WIH);
  const float* bias = (const float*)(ws + F_BIAS);
  unsigned short* xproj = (unsigned short*)(ws + F_XPROJ);

  __shared__ __align__(16) unsigned char smem[65536];
  const int tid = threadIdx.x;
  const int w = tid >> 6, l = tid & 63;
  const int mh = w & 1, nh = w >> 1;
  const int bid = blockIdx.x;
  const int t = bid >> 7, mtile = (bid >> 4) & 7, ntile = bid & 15;

  f32x4 acc[4][4];
  {
    f32x4 z = {0.f, 0.f, 0.f, 0.f};
    #pragma unroll
    for (int i = 0; i < 4; ++i)
      #pragma unroll
      for (int j = 0; j < 4; ++j) acc[i][j] = z;
  }

  auto stage = [&](int kc, int buf) {
    unsigned char* ab = smem + buf * 16384;
    unsigned char* bb = smem + 32768 + buf * 16384;
    #pragma unroll
    for (int j = 0; j < 4; ++j) {
      int idx = w * 4 + j;
      int mb_l = idx >> 1, ksl = idx & 1;
      size_t frag = (size_t)(t * 64 + mtile * 8 + mb_l) * 16u + kc * 2 + ksl;
      gl_lds16(xbf + (frag * 64u + l) * 8u, ab + idx * 1024);
    }
    #pragma unroll
    for (int j = 0; j < 4; ++j) {
      int idx = w * 4 + j;
      int cb_l = idx >> 1, ksl = idx & 1;
      size_t frag = (size_t)(ntile * 8 + cb_l) * 16u + kc * 2 + ksl;
      gl_lds16(wih + (frag * 64u + l) * 8u, bb + idx * 1024);
    }
  };

  stage(0, 0);
  __syncthreads();
  for (int kc = 0; kc < 8; ++kc) {
    int cur = kc & 1;
    if (kc < 7) stage(kc + 1, cur ^ 1);
    unsigned char* ab = smem + cur * 16384;
    unsigned char* bb = smem + 32768 + cur * 16384;
    s16x8 afr[4][2], bfr[4][2];
    #pragma unroll
    for (int m = 0; m < 4; ++m)
      #pragma unroll
      for (int ksl = 0; ksl < 2; ++ksl)
        afr[m][ksl] = *(const s16x8*)(ab + ((mh * 4 + m) * 2 + ksl) * 1024 + l * 16);
    #pragma unroll
    for (int n = 0; n < 4; ++n)
      #pragma unroll
      for (int ksl = 0; ksl < 2; ++ksl)
        bfr[n][ksl] = *(const s16x8*)(bb + ((nh * 4 + n) * 2 + ksl) * 1024 + l * 16);
    #pragma unroll
    for (int m = 0; m < 4; ++m)
      #pragma unroll
      for (int n = 0; n < 4; ++n)
        #pragma unroll
        for (int ksl = 0; ksl < 2; ++ksl)
          acc[m][n] = __builtin_amdgcn_mfma_f32_16x16x32_bf16(
              afr[m][ksl], bfr[n][ksl], acc[m][n], 0, 0, 0);
    __syncthreads();
  }

  #pragma unroll
  for (int m = 0; m < 4; ++m) {
    int mb_abs = mtile * 8 + mh * 4 + m;
    #pragma unroll
    for (int n = 0; n < 4; ++n) {
      int n_abs = ntile * 8 + nh * 4 + n;
      float bc = bias[n_abs * 16 + (l & 15)];
      u16x4 p;
      #pragma unroll
      for (int r = 0; r < 4; ++r) p[r] = f2bf(acc[m][n][r] + bc);
      *(u16x4*)(xproj + ((size_t)(t * 64 + mb_abs) * 128u + n_abs) * 256u + l * 4u) = p;
    }
  }
}

// Persistent spin-barrier recurrence: 256 blocks x 512 threads, 1 block/CU.
// mt = blockIdx&15, ht = blockIdx>>4. Block: 64 rows x 32 h-cols.
// Wave w: (mbw=w>>1, cbl=w&1) -> 16 rows x 16 cols.
// LDS: [0,128K) W frags; Hl f32[64][40]; Cl f32[64][40]; dn16 bf16[64][72].
#define P_HL  131072
#define P_CL  141312
#define P_DN  151552
__global__ void __launch_bounds__(512, 2) persist_lock(
    const float* __restrict__ rnn, const float* __restrict__ dones,
    unsigned char* __restrict__ ws, float* __restrict__ out) {
  const unsigned short* whh = (const unsigned short*)(ws + F_WHH);
  const unsigned short* xproj = (const unsigned short*)(ws + F_XPROJ);
  unsigned int* ctrs = (unsigned int*)(ws + F_CTR);
  unsigned long long* hq0 = (unsigned long long*)(ws + F_HF0);
  unsigned long long* hq1 = (unsigned long long*)(ws + F_HF1);

  __shared__ __align__(16) unsigned char smem[160768];
  float* Hl = (float*)(smem + P_HL);
  float* Cl = (float*)(smem + P_CL);
  unsigned short* dn16 = (unsigned short*)(smem + P_DN);

  const int tid = threadIdx.x;
  const int w = tid >> 6, l = tid & 63;
  const int mbw = w >> 1, cbl = w & 1;
  const int mt = (int)blockIdx.x & 15, ht = (int)blockIdx.x >> 4;

  // ---- prologue: W tile -> LDS, dones -> bf16 LDS, c0 -> regs ----
  #pragma unroll
  for (int j = 0; j < 16; ++j) {
    int idx = w * 16 + j;
    int gcb = idx >> 4, ks = idx & 15;
    int cb = (gcb >> 1) * 32 + ht * 2 + (gcb & 1);
    gl_lds16(whh + ((size_t)(cb * 16 + ks) * 64u + l) * 8u, smem + idx * 1024);
  }
  {
    const float* dsrc = dones + (size_t)mt * 4096u + tid * 8;
    f32x4 d0 = *(const f32x4*)dsrc, d1 = *(const f32x4*)(dsrc + 4);
    int row = tid >> 3, t0 = (tid & 7) * 8;
    u32x4 p;
    p.x = pack2(d0.x, d0.y); p.y = pack2(d0.z, d0.w);
    p.z = pack2(d1.x, d1.y); p.w = pack2(d1.z, d1.w);
    *(u32x4*)(dn16 + row * 72 + t0) = p;
  }
  f32x4 cold;
  #pragma unroll
  for (int r = 0; r < 4; ++r) {
    int b = mt * 64 + mbw * 16 + ((l >> 4) << 2) + r;
    cold[r] = rnn[(size_t)b * 1024u + 512u + ht * 32 + cbl * 16 + (l & 15)];
  }
  __syncthreads();

  #pragma unroll 1
  for (int t = 0; t < 64; ++t) {
    const unsigned long long* hsrc = (t & 1) ? hq1 : hq0;
    unsigned long long* hdst = (t & 1) ? hq0 : hq1;

    // A operand: wave's mb frags, SPLIT-u64 coherent loads (dense/coalesced)
    s16x8 areg[16];
    #pragma unroll
    for (int ks = 0; ks < 16; ++ks) {
      size_t f = (size_t)((mt * 4 + mbw) * 16 + ks) * 128u;
      union { unsigned long long q[2]; s16x8 v; } u;
      u.q[0] = __hip_atomic_load(hsrc + f + l,
                                 __ATOMIC_RELAXED, __HIP_MEMORY_SCOPE_AGENT);
      u.q[1] = __hip_atomic_load(hsrc + f + 64u + l,
                                 __ATOMIC_RELAXED, __HIP_MEMORY_SCOPE_AGENT);
      areg[ks] = u.v;
    }
    // xproj loads issued now; consumed AFTER the MFMA phase (latency hidden)
    u16x4 xq[4];
    #pragma unroll
    for (int g = 0; g < 4; ++g) {
      int n_abs = g * 32 + ht * 2 + cbl;
      xq[g] = __builtin_nontemporal_load((const u16x4*)(xproj +
          ((size_t)(t * 64 + mt * 4 + mbw) * 128u + n_abs) * 256u + l * 4u));
    }

    f32x4 acc[4];
    {
      f32x4 z = {0.f, 0.f, 0.f, 0.f};
      #pragma unroll
      for (int g = 0; g < 4; ++g) acc[g] = z;
    }
    #pragma unroll
    for (int ks = 0; ks < 16; ++ks) {
      s16x8 bfr[4];
      #pragma unroll
      for (int g = 0; g < 4; ++g)
        bfr[g] = *(const s16x8*)(smem + ((g * 2 + cbl) * 16 + ks) * 1024 + l * 16);
      #pragma unroll
      for (int g = 0; g < 4; ++g)
        acc[g] = __builtin_amdgcn_mfma_f32_16x16x32_bf16(areg[ks], bfr[g], acc[g], 0, 0, 0);
    }
    #pragma unroll
    for (int g = 0; g < 4; ++g)
      #pragma unroll
      for (int r = 0; r < 4; ++r) acc[g][r] += bf2f(xq[g][r]);

    // ---- LSTM cell: h,c (unmasked) -> LDS; masked c -> regs ----
    #pragma unroll
    for (int r = 0; r < 4; ++r) {
      float gi = sigm(acc[0][r]);
      float gf = sigm(acc[1][r]);
      float gg = tanhf(acc[2][r]);
      float go = sigm(acc[3][r]);
      int lrow = mbw * 16 + ((l >> 4) << 2) + r;
      float cc = gf * cold[r] + gi * gg;
      float h = go * tanhf(cc);
      float keep = 1.0f - bf2f(dn16[lrow * 72 + t]);   // next step's mask
      cold[r] = cc * keep;
      Hl[lrow * 40 + cbl * 16 + (l & 15)] = h;
      Cl[lrow * 40 + cbl * 16 + (l & 15)] = cc;
    }
    __syncthreads();   // Hl/Cl complete; areg reads done

    if (t < 63) {
      // repack masked h -> hdst frags (SPLIT-u64 coherent stores)
      if (tid < 256) {
        const int mbl = tid >> 6, lp = tid & 63;
        const int row = mbl * 16 + (lp & 15);
        const float keep = 1.0f - bf2f(dn16[row * 72 + t]);
        const float* hr = Hl + (size_t)row * 40u + ((lp >> 4) << 3);
        union { u32x4 v; unsigned long long q[2]; } u;
        u.v.x = pack2(hr[0] * keep, hr[1] * keep);
        u.v.y = pack2(hr[2] * keep, hr[3] * keep);
        u.v.z = pack2(hr[4] * keep, hr[5] * keep);
        u.v.w = pack2(hr[6] * keep, hr[7] * keep);
        size_t f = (size_t)((mt * 4 + mbl) * 16 + ht) * 128u;
        __hip_atomic_store(hdst + f + lp, u.q[0],
                           __ATOMIC_RELAXED, __HIP_MEMORY_SCOPE_AGENT);
        __hip_atomic_store(hdst + f + 64u + lp, u.q[1],
                           __ATOMIC_RELAXED, __HIP_MEMORY_SCOPE_AGENT);
      }
      __syncthreads();   // per-wave vmcnt(0) drain: repack stores at MALL

      // ---- per-mt spin barrier; outputs issued AFTER release ----
      if (tid == 0) {
        unsigned int* ctr = ctrs + mt * 32;
        __hip_atomic_fetch_add(ctr, 1u, __ATOMIC_RELEASE, __HIP_MEMORY_SCOPE_AGENT);
        unsigned int target = 16u * (unsigned int)(t + 1);
        while (__hip_atomic_load(ctr, __ATOMIC_ACQUIRE, __HIP_MEMORY_SCOPE_AGENT) < target)
          __builtin_amdgcn_s_sleep(1);
      }
      // outputs for step t (drain under next step's loads/MFMA)
      {
        int row = tid >> 3, chn = tid & 7;
        int b = mt * 64 + row;
        f32x4 hv = *(const f32x4*)(Hl + row * 40 + chn * 4);
        f32x4 cv = *(const f32x4*)(Cl + row * 40 + chn * 4);
        int colg = ht * 32 + chn * 4;
        __builtin_nontemporal_store(hv, (f32x4*)(out + ((size_t)(b * 64 + t)) * 512u + colg));
        __builtin_nontemporal_store(hv, (f32x4*)(out + OUT_HS + ((size_t)(t * 1024 + b)) * 512u + colg));
        __builtin_nontemporal_store(cv, (f32x4*)(out + OUT_CS + ((size_t)(t * 1024 + b)) * 512u + colg));
      }
      lds_barrier();   // join: LDS reads drained; vmem stores NOT drained
    } else {
      // final step: outputs + rnn_states, no barrier needed
      int row = tid >> 3, chn = tid & 7;
      int b = mt * 64 + row;
      f32x4 hv = *(const f32x4*)(Hl + row * 40 + chn * 4);
      f32x4 cv = *(const f32x4*)(Cl + row * 40 + chn * 4);
      int colg = ht * 32 + chn * 4;
      __builtin_nontemporal_store(hv, (f32x4*)(out + ((size_t)(b * 64 + t)) * 512u + colg));
      __builtin_nontemporal_store(hv, (f32x4*)(out + OUT_HS + ((size_t)(t * 1024 + b)) * 512u + colg));
      __builtin_nontemporal_store(cv, (f32x4*)(out + OUT_CS + ((size_t)(t * 1024 + b)) * 512u + colg));
      __builtin_nontemporal_store(hv, (f32x4*)(out + OUT_RNN + (size_t)b * 1024u + colg));
      __builtin_nontemporal_store(cv, (f32x4*)(out + OUT_RNN + (size_t)b * 1024u + 512u + colg));
    }
  }
}

// ====================== FALLBACK (round-1, verified) ======================

__global__ void __launch_bounds__(256) prep_kernel(
    const float* __restrict__ rnn, const float* __restrict__ Wih,
    const float* __restrict__ Whh, const float* __restrict__ bih,
    const float* __restrict__ bhh, unsigned char* __restrict__ ws) {
  unsigned int tid = blockIdx.x * 256u + threadIdx.x;
  unsigned short* wcf = (unsigned short*)(ws + WC_OFF);
  unsigned short* hf  = (unsigned short*)(ws + HF_OFF);
  float* cf   = (float*)(ws + CF_OFF);
  float* bias = (float*)(ws + BIAS_OFF);
  if (tid < 262144u) {
    unsigned int frag = tid >> 6, l = tid & 63u;
    unsigned int cb = frag >> 5, ks = frag & 31u;
    unsigned int g  = cb * 16u + (l & 15u);
    unsigned int k0 = ks * 32u + ((l >> 4) << 3);
    const float* src = (k0 < 512u) ? (Wih + g * 512u + k0) : (Whh + g * 512u + (k0 - 512u));
    u32x4 p;
    p.x = pack2(src[0], src[1]); p.y = pack2(src[2], src[3]);
    p.z = pack2(src[4], src[5]); p.w = pack2(src[6], src[7]);
    *(u32x4*)(wcf + (size_t)frag * 512u + l * 8u) = p;
  } else if (tid < 327680u) {
    unsigned int t2 = tid - 262144u;
    unsigned int frag = t2 >> 6, l = t2 & 63u;
    unsigned int mb = frag >> 4, ks = frag & 15u;
    unsigned int b  = mb * 16u + (l & 15u);
    unsigned int c0 = ks * 32u + ((l >> 4) << 3);
    const float* src = rnn + (size_t)b * 1024u + c0;
    u32x4 p;
    p.x = pack2(src[0], src[1]); p.y = pack2(src[2], src[3]);
    p.z = pack2(src[4], src[5]); p.w = pack2(src[6], src[7]);
    *(u32x4*)(hf + (size_t)frag * 512u + l * 8u) = p;
  } else if (tid < 458752u) {
    unsigned int t2 = tid - 327680u;
    unsigned int frag = t2 >> 6, l = t2 & 63u;
    unsigned int mb = frag >> 5, cfi = frag & 31u;
    unsigned int hcol = cfi * 16u + (l & 15u);
    f32x4 p;
    #pragma unroll
    for (int r = 0; r < 4; ++r) {
      unsigned int b = mb * 16u + ((l >> 4) << 2) + r;
      p[r] = rnn[(size_t)b * 1024u + 512u + hcol];
    }
    *(f32x4*)(cf + (size_t)frag * 256u + l * 4u) = p;
  } else if (tid < 460800u) {
    unsigned int g = tid - 458752u;
    bias[g] = bih[g] + bhh[g];
  }
}

__global__ void __launch_bounds__(256) step_kernel(
    const float* __restrict__ xg, const float* __restrict__ dones,
    unsigned char* __restrict__ ws, float* __restrict__ out, int t) {
  const unsigned short* wcf = (const unsigned short*)(ws + WC_OFF);
  unsigned short* hf = (unsigned short*)(ws + HF_OFF);
  float* cf = (float*)(ws + CF_OFF);
  const float* bias = (const float*)(ws + BIAS_OFF);

  __shared__ __align__(16) unsigned char smem[49152];
  const int tid = threadIdx.x;
  const int w = tid >> 6, l = tid & 63;
  const int mh = w & 1, ch = w >> 1;
  const int mt = (int)blockIdx.x >> 4, ht = (int)blockIdx.x & 15;

  f32x4 acc[2][4];
  {
    f32x4 z = {0.f, 0.f, 0.f, 0.f};
    #pragma unroll
    for (int i = 0; i < 2; ++i)
      #pragma unroll
      for (int j = 0; j < 4; ++j) acc[i][j] = z;
  }

  f32x4 xv[2][2];

  auto stage_load = [&](int kc, int buf) {
    unsigned char* bb = smem + 16384 + buf * 16384;
    #pragma unroll
    for (int j = 0; j < 4; ++j) {
      int idx = w * 4 + j;
      int g = idx >> 2, cbl = (idx >> 1) & 1, ksl = idx & 1;
      int cb = g * 32 + ht * 2 + cbl;
      int ks = kc * 2 + ksl;
      const unsigned short* src = wcf + ((size_t)(cb * 32 + ks) * 64u + l) * 8u;
      gl_lds16(src, bb + idx * 1024);
    }
    unsigned char* ab = smem + buf * 8192;
    if (kc >= 8) {
      #pragma unroll
      for (int j = 0; j < 2; ++j) {
        int idx = w * 2 + j;
        int ksh = (kc - 8) * 2 + j;
        int mb_abs = mt * 4 + w;
        const unsigned short* src = hf + ((size_t)(mb_abs * 16 + ksh) * 64u + l) * 8u;
        gl_lds16(src, ab + idx * 1024);
      }
    } else {
      #pragma unroll
      for (int j = 0; j < 2; ++j) {
        int ks = kc * 2 + j;
        int b = mt * 64 + w * 16 + (l & 15);
        int k0 = ks * 32 + ((l >> 4) << 3);
        const float* src = xg + ((size_t)(b * 64 + t)) * 512u + k0;
        xv[j][0] = *(const f32x4*)src;
        xv[j][1] = *(const f32x4*)(src + 4);
      }
    }
  };
  auto stage_write = [&](int kc, int buf) {
    if (kc < 8) {
      unsigned char* ab = smem + buf * 8192;
      #pragma unroll
      for (int j = 0; j < 2; ++j) {
        int idx = w * 2 + j;
        u32x4 p;
        p.x = pack2(xv[j][0].x, xv[j][0].y); p.y = pack2(xv[j][0].z, xv[j][0].w);
        p.z = pack2(xv[j][1].x, xv[j][1].y); p.w = pack2(xv[j][1].z, xv[j][1].w);
        *(u32x4*)(ab + idx * 1024 + l * 16) = p;
      }
    }
  };

  stage_load(0, 0);
  stage_write(0, 0);
  __syncthreads();

  for (int kc = 0; kc < 16; ++kc) {
    int cur = kc & 1;
    if (kc < 15) stage_load(kc + 1, cur ^ 1);
    unsigned char* ab = smem + cur * 8192;
    unsigned char* bb = smem + 16384 + cur * 16384;
    s16x8 afr[2][2], bfr[4][2];
    #pragma unroll
    for (int mb2 = 0; mb2 < 2; ++mb2)
      #pragma unroll
      for (int ksl = 0; ksl < 2; ++ksl)
        afr[mb2][ksl] = *(const s16x8*)(ab + ((mh * 2 + mb2) * 2 + ksl) * 1024 + l * 16);
    #pragma unroll
    for (int g = 0; g < 4; ++g)
      #pragma unroll
      for (int ksl = 0; ksl < 2; ++ksl)
        bfr[g][ksl] = *(const s16x8*)(bb + (g * 4 + ch * 2 + ksl) * 1024 + l * 16);
    #pragma unroll
    for (int mb2 = 0; mb2 < 2; ++mb2)
      #pragma unroll
      for (int g = 0; g < 4; ++g)
        #pragma unroll
        for (int ksl = 0; ksl < 2; ++ksl)
          acc[mb2][g] = __builtin_amdgcn_mfma_f32_16x16x32_bf16(
              afr[mb2][ksl], bfr[g][ksl], acc[mb2][g], 0, 0, 0);
    if (kc < 15) stage_write(kc + 1, cur ^ 1);
    __syncthreads();
  }

  const int hcol = ht * 32 + ch * 16 + (l & 15);
  const float bi = bias[hcol], bf2 = bias[512 + hcol];
  const float bg = bias[1024 + hcol], bo = bias[1536 + hcol];
  float* Hl = (float*)smem;
  float* Cl = (float*)(smem + 9216);
  const int cfi = ht * 2 + ch;
  const int colL = ch * 16 + (l & 15);
  #pragma unroll
  for (int mb2 = 0; mb2 < 2; ++mb2) {
    const int mb_abs = mt * 4 + mh * 2 + mb2;
    const int fid = mb_abs * 32 + cfi;
    f32x4 cold = *(const f32x4*)(cf + (size_t)fid * 256u + l * 4u);
    f32x4 cmask;
    #pragma unroll
    for (int r = 0; r < 4; ++r) {
      float gi = sigm(acc[mb2][0][r] + bi);
      float gf = sigm(acc[mb2][1][r] + bf2);
      float gg = tanhf(acc[mb2][2][r] + bg);
      float go = sigm(acc[mb2][3][r] + bo);
      float c = gf * cold[r] + gi * gg;
      float h = go * tanhf(c);
      int brow = mb_abs * 16 + ((l >> 4) << 2) + r;
      float keep = 1.0f - dones[brow * 64 + t];
      cmask[r] = c * keep;
      int rowL = mh * 32 + mb2 * 16 + ((l >> 4) << 2) + r;
      Hl[rowL * 36 + colL] = h;
      Cl[rowL * 36 + colL] = c;
    }
    *(f32x4*)(cf + (size_t)fid * 256u + l * 4u) = cmask;
  }
  __syncthreads();

  {
    const int mb2f = tid >> 6, lp = tid & 63;
    const int mb_abs = mt * 4 + mb2f;
    const int rowL = mb2f * 16 + (lp & 15);
    const int c0 = (lp >> 4) << 3;
    const int brow = mt * 64 + rowL;
    const float keep = 1.0f - dones[brow * 64 + t];
    const float* hr = Hl + rowL * 36 + c0;
    u32x4 p;
    p.x = pack2(hr[0] * keep, hr[1] * keep);
    p.y = pack2(hr[2] * keep, hr[3] * keep);
    p.z = pack2(hr[4] * keep, hr[5] * keep);
    p.w = pack2(hr[6] * keep, hr[7] * keep);
    *(u32x4*)(hf + ((size_t)(mb_abs * 16 + ht) * 64u + lp) * 8u) = p;
  }
  {
    const int row = tid & 63, cg2 = tid >> 6;
    const int b = mt * 64 + row;
    const int c0 = cg2 * 8;
    const float* hr = Hl + row * 36 + c0;
    const float* cr = Cl + row * 36 + c0;
    f32x4 h0 = *(const f32x4*)hr,  h1 = *(const f32x4*)(hr + 4);
    f32x4 cc0 = *(const f32x4*)cr, cc1 = *(const f32x4*)(cr + 4);
    const int colg = ht * 32 + c0;
    size_t xoff = ((size_t)(b * 64 + t)) * 512u + colg;
    *(f32x4*)(out + xoff) = h0; *(f32x4*)(out + xoff + 4) = h1;
    size_t hoff = OUT_HS + ((size_t)(t * 1024 + b)) * 512u + colg;
    *(f32x4*)(out + hoff) = h0; *(f32x4*)(out + hoff + 4) = h1;
    size_t coff = OUT_CS + ((size_t)(t * 1024 + b)) * 512u + colg;
    *(f32x4*)(out + coff) = cc0; *(f32x4*)(out + coff + 4) = cc1;
    if (t == 63) {
      size_t roff = OUT_RNN + (size_t)b * 1024u + colg;
      *(f32x4*)(out + roff) = h0;        *(f32x4*)(out + roff + 4) = h1;
      *(f32x4*)(out + roff + 512) = cc0; *(f32x4*)(out + roff + 516) = cc1;
    }
  }
}

extern "C" void kernel_launch(void* const* d_in, const int* in_sizes, int n_in,
                              void* d_out, int out_size, void* d_ws, size_t ws_size,
                              hipStream_t stream) {
  const float* xg  = (const float*)d_in[0];
  const float* rnn = (const float*)d_in[1];
  const float* dn  = (const float*)d_in[2];
  const float* Wih = (const float*)d_in[3];
  const float* Whh = (const float*)d_in[4];
  const float* bih = (const float*)d_in[5];
  const float* bhh = (const float*)d_in[6];
  float* out = (float*)d_out;
  unsigned char* ws = (unsigned char*)d_ws;
  (void)in_sizes; (void)n_in; (void)out_size;

  if (ws_size >= (size_t)F_NEED) {
    prep_fast<<<17680, 256, 0, stream>>>(xg, rnn, Wih, Whh, bih, bhh, ws);
    gemm_xproj<<<8192, 256, 0, stream>>>(ws);
    persist_lock<<<256, 512, 0, stream>>>(rnn, dn, ws, out);
  } else {
    prep_kernel<<<1800, 256, 0, stream>>>(rnn, Wih, Whh, bih, bhh, ws);
    for (int t = 0; t < 64; ++t)
      step_kernel<<<256, 256, 0, stream>>>(xg, dn, ws, out, t);
  }
}